// Round 1
// baseline (2864.363 us; speedup 1.0000x reference)
//
#include <hip/hip_runtime.h>
#include <math.h>

#define B_ 2
#define S_ 2048
#define M_ 1024
#define H_ 16
#define D_ 64
#define R_ (B_*S_)          // 4096 rows
#define NEGBIG (-1e9f)

__device__ __forceinline__ float4 ld4(const float* p) {
    return *(const float4* __restrict__)p;
}

// ---------------------------------------------------------------------------
// Generic tiled fp32 GEMM: C[Mr x N] = A[Mr x K] @ B + bias (+ReLU)
// BLAY:  0 = B row-major [K][N]
//        1 = head-stacked  W[H][K][64], logical B[k][h*64+d]
// OUTLAY:0 = row-major C[row][n]
//        1 = BHSD: row=b*S+s, n=h*64+d -> C[((b*H+h)*S+s)*64+d]
// ACT:   0 = none, 1 = ReLU
// Tiles: BM=BN=64, BK=32, 256 threads, 4x4 per thread.
// ---------------------------------------------------------------------------
template<int BLAY, int OUTLAY, int ACT>
__global__ __launch_bounds__(256) void gemm_k(
    const float* __restrict__ A, const float* __restrict__ Bw,
    const float* __restrict__ bias, float* __restrict__ C,
    int Mr, int N, int K)
{
    __shared__ __align__(16) float As[64][36];   // padded: reads As[m][kk] conflict-lite
    __shared__ __align__(16) float Bs[32][64];
    const int tid = threadIdx.x;
    const int tx = tid & 15, ty = tid >> 4;
    const int m0 = blockIdx.y * 64, n0 = blockIdx.x * 64;

    const int alr = tid >> 3;            // 0..31  (A rows alr, alr+32)
    const int alc = (tid & 7) << 2;      // 0..28  (A k-cols, float4)
    const int bkr = tid >> 4;            // 0..15  (B k-rows bkr, bkr+16)
    const int bnc = (tid & 15) << 2;     // 0..60  (B n-cols, float4)

    float acc[4][4] = {};

    for (int k0 = 0; k0 < K; k0 += 32) {
        float4 a0 = ld4(&A[(size_t)(m0 + alr)      * K + k0 + alc]);
        float4 a1 = ld4(&A[(size_t)(m0 + alr + 32) * K + k0 + alc]);
        float4 b0, b1;
        if (BLAY == 0) {
            b0 = ld4(&Bw[(size_t)(k0 + bkr)      * N + n0 + bnc]);
            b1 = ld4(&Bw[(size_t)(k0 + bkr + 16) * N + n0 + bnc]);
        } else {
            const int h = n0 >> 6;       // BN=64 => one head per block column
            b0 = ld4(&Bw[((size_t)h * K + k0 + bkr)      * 64 + bnc]);
            b1 = ld4(&Bw[((size_t)h * K + k0 + bkr + 16) * 64 + bnc]);
        }
        *(float4*)&As[alr][alc]      = a0;
        *(float4*)&As[alr + 32][alc] = a1;
        *(float4*)&Bs[bkr][bnc]      = b0;
        *(float4*)&Bs[bkr + 16][bnc] = b1;
        __syncthreads();

        #pragma unroll
        for (int kk = 0; kk < 32; ++kk) {
            float a[4], b[4];
            #pragma unroll
            for (int i = 0; i < 4; ++i) a[i] = As[ty * 4 + i][kk];
            #pragma unroll
            for (int j = 0; j < 4; ++j) b[j] = Bs[kk][tx * 4 + j];
            #pragma unroll
            for (int i = 0; i < 4; ++i)
                #pragma unroll
                for (int j = 0; j < 4; ++j)
                    acc[i][j] = fmaf(a[i], b[j], acc[i][j]);
        }
        __syncthreads();
    }

    #pragma unroll
    for (int i = 0; i < 4; ++i) {
        const int row = m0 + ty * 4 + i;
        #pragma unroll
        for (int j = 0; j < 4; ++j) {
            const int n = n0 + tx * 4 + j;
            float v = acc[i][j] + bias[n];
            if (ACT == 1) v = fmaxf(v, 0.f);
            acc[i][j] = v;
        }
        float4 cv = make_float4(acc[i][0], acc[i][1], acc[i][2], acc[i][3]);
        if (OUTLAY == 0) {
            *(float4*)&C[(size_t)row * N + n0 + tx * 4] = cv;
        } else {
            const int b = row >> 11;          // S_ = 2048
            const int s = row & 2047;
            const int h = n0 >> 6;
            *(float4*)&C[(((size_t)(b * H_ + h)) * S_ + s) * D_ + tx * 4] = cv;
        }
    }
}

// ---------------------------------------------------------------------------
// Flash-style fp32 attention. Q,K,V in [B,H,S,64]; O row-major [B*S, 1024]
// (heads concatenated). Block = 64 q-rows, 256 threads: thread t owns
// row r=t>>2, d-segment seg=t&3 (16 d's). Scores reduced across the 4
// row-threads with shfl_xor(1|2). Online softmax, K/V tiles of 32 in LDS.
// ---------------------------------------------------------------------------
template<int CAUSAL>
__global__ __launch_bounds__(256) void attn_k(
    const float* __restrict__ Q, const float* __restrict__ K,
    const float* __restrict__ V, float* __restrict__ O, int Skv)
{
    __shared__ __align__(16) float Ks[32][64];
    __shared__ __align__(16) float Vs[32][64];
    const int tid = threadIdx.x;
    const int r = tid >> 2, seg = tid & 3, s16 = seg * 16;
    const int q0 = blockIdx.x * 64;
    const int bh = blockIdx.y;
    const int b = bh >> 4, h = bh & 15;
    const float* Qb = Q + ((size_t)bh * S_ + q0) * D_;
    const float* Kb = K + (size_t)bh * Skv * D_;
    const float* Vb = V + (size_t)bh * Skv * D_;

    float qr[16];
    #pragma unroll
    for (int i4 = 0; i4 < 4; ++i4) {
        float4 t = ld4(Qb + r * D_ + s16 + i4 * 4);
        qr[i4*4+0] = t.x; qr[i4*4+1] = t.y; qr[i4*4+2] = t.z; qr[i4*4+3] = t.w;
    }
    const int qg = q0 + r;
    float m = -1e30f, l = 0.f, o[16];
    #pragma unroll
    for (int i = 0; i < 16; ++i) o[i] = 0.f;

    const int ktiles = CAUSAL ? ((q0 + 64) >> 5) : (Skv >> 5);
    const int lkr = tid >> 3;            // 0..31
    const int lkc = (tid & 7) << 2;      // 0..28 (+32 for second half)

    for (int kt = 0; kt < ktiles; ++kt) {
        const int kbase = kt * 32;
        float4 kv0 = ld4(Kb + (size_t)(kbase + lkr) * D_ + lkc);
        float4 kv1 = ld4(Kb + (size_t)(kbase + lkr) * D_ + lkc + 32);
        float4 vv0 = ld4(Vb + (size_t)(kbase + lkr) * D_ + lkc);
        float4 vv1 = ld4(Vb + (size_t)(kbase + lkr) * D_ + lkc + 32);
        __syncthreads();                      // prior-tile reads done
        *(float4*)&Ks[lkr][lkc]      = kv0;
        *(float4*)&Ks[lkr][lkc + 32] = kv1;
        *(float4*)&Vs[lkr][lkc]      = vv0;
        *(float4*)&Vs[lkr][lkc + 32] = vv1;
        __syncthreads();

        float s[32];
        #pragma unroll 8
        for (int j = 0; j < 32; ++j) {
            float p = 0.f;
            #pragma unroll
            for (int i4 = 0; i4 < 4; ++i4) {
                float4 kk = ld4(&Ks[j][s16 + i4 * 4]);
                p = fmaf(qr[i4*4+0], kk.x, p);
                p = fmaf(qr[i4*4+1], kk.y, p);
                p = fmaf(qr[i4*4+2], kk.z, p);
                p = fmaf(qr[i4*4+3], kk.w, p);
            }
            p += __shfl_xor(p, 1);
            p += __shfl_xor(p, 2);
            p *= 0.125f;                      // 1/sqrt(64)
            if (CAUSAL && (kbase + j > qg)) p = NEGBIG;
            s[j] = p;
        }
        float tm = s[0];
        #pragma unroll
        for (int j = 1; j < 32; ++j) tm = fmaxf(tm, s[j]);
        const float nm = fmaxf(m, tm);
        const float f = __expf(m - nm);
        float ls = 0.f;
        #pragma unroll
        for (int j = 0; j < 32; ++j) { s[j] = __expf(s[j] - nm); ls += s[j]; }
        l = l * f + ls;
        m = nm;
        #pragma unroll
        for (int i = 0; i < 16; ++i) o[i] *= f;
        #pragma unroll 8
        for (int j = 0; j < 32; ++j) {
            const float pj = s[j];
            #pragma unroll
            for (int i4 = 0; i4 < 4; ++i4) {
                float4 vv = ld4(&Vs[j][s16 + i4 * 4]);
                o[i4*4+0] = fmaf(pj, vv.x, o[i4*4+0]);
                o[i4*4+1] = fmaf(pj, vv.y, o[i4*4+1]);
                o[i4*4+2] = fmaf(pj, vv.z, o[i4*4+2]);
                o[i4*4+3] = fmaf(pj, vv.w, o[i4*4+3]);
            }
        }
    }

    const float inv = 1.f / l;
    float* orow = O + ((size_t)(b * S_ + q0 + r)) * M_ + h * D_ + s16;
    #pragma unroll
    for (int i4 = 0; i4 < 4; ++i4) {
        float4 t = make_float4(o[i4*4]*inv, o[i4*4+1]*inv, o[i4*4+2]*inv, o[i4*4+3]*inv);
        *(float4*)(orow + i4 * 4) = t;
    }
}

// ---------------------------------------------------------------------------
// Fused residual-add + LayerNorm over rows of 1024. One 256-thread block/row.
// out = LN(X + Rz) * g + beta
// ---------------------------------------------------------------------------
__global__ __launch_bounds__(256) void ln_k(
    const float* __restrict__ X, const float* __restrict__ Rz,
    const float* __restrict__ g, const float* __restrict__ be,
    float* __restrict__ out)
{
    __shared__ float red[8];
    const int row = blockIdx.x, tid = threadIdx.x;
    const int lane = tid & 63, w = tid >> 6;

    float4 x  = ld4(X  + (size_t)row * M_ + tid * 4);
    float4 rr = ld4(Rz + (size_t)row * M_ + tid * 4);
    x.x += rr.x; x.y += rr.y; x.z += rr.z; x.w += rr.w;

    float sm = x.x + x.y + x.z + x.w;
    #pragma unroll
    for (int off = 1; off < 64; off <<= 1) sm += __shfl_xor(sm, off);
    if (lane == 0) red[w] = sm;
    __syncthreads();
    const float mean = (red[0] + red[1] + red[2] + red[3]) * (1.f / M_);

    x.x -= mean; x.y -= mean; x.z -= mean; x.w -= mean;
    float vs = x.x*x.x + x.y*x.y + x.z*x.z + x.w*x.w;
    #pragma unroll
    for (int off = 1; off < 64; off <<= 1) vs += __shfl_xor(vs, off);
    if (lane == 0) red[4 + w] = vs;
    __syncthreads();
    const float var = (red[4] + red[5] + red[6] + red[7]) * (1.f / M_);
    const float rs = rsqrtf(var + 1e-5f);

    float4 gg = ld4(g + tid * 4), bb = ld4(be + tid * 4);
    float4 y = make_float4(x.x * rs * gg.x + bb.x,
                           x.y * rs * gg.y + bb.y,
                           x.z * rs * gg.z + bb.z,
                           x.w * rs * gg.w + bb.w);
    *(float4*)(out + (size_t)row * M_ + tid * 4) = y;
}

// ---------------------------------------------------------------------------
extern "C" void kernel_launch(void* const* d_in, const int* in_sizes, int n_in,
                              void* d_out, int out_size, void* d_ws, size_t ws_size,
                              hipStream_t stream)
{
    const float* input = (const float*)d_in[0];
    const float* enc   = (const float*)d_in[1];
    const float* Wq1 = (const float*)d_in[2];  const float* bq1 = (const float*)d_in[3];
    const float* Wk1 = (const float*)d_in[4];  const float* bk1 = (const float*)d_in[5];
    const float* Wv1 = (const float*)d_in[6];  const float* bv1 = (const float*)d_in[7];
    const float* Wo1 = (const float*)d_in[8];  const float* bo1 = (const float*)d_in[9];
    const float* ln1g = (const float*)d_in[10]; const float* ln1b = (const float*)d_in[11];
    const float* Wq2 = (const float*)d_in[12]; const float* bq2 = (const float*)d_in[13];
    const float* Wk2 = (const float*)d_in[14]; const float* bk2 = (const float*)d_in[15];
    const float* Wv2 = (const float*)d_in[16]; const float* bv2 = (const float*)d_in[17];
    const float* Wo2 = (const float*)d_in[18]; const float* bo2 = (const float*)d_in[19];
    const float* ln2g = (const float*)d_in[20]; const float* ln2b = (const float*)d_in[21];
    const float* Wf1 = (const float*)d_in[22]; const float* bf1 = (const float*)d_in[23];
    const float* Wf2 = (const float*)d_in[24]; const float* bf2 = (const float*)d_in[25];
    const float* ln3g = (const float*)d_in[26]; const float* ln3b = (const float*)d_in[27];

    float* out = (float*)d_out;
    float* ws  = (float*)d_ws;
    const size_t SZ = (size_t)R_ * M_;       // 4 Mi floats = 16 MB

    float* bufQ   = ws;                      // [B,H,S,D]
    float* bufK   = ws + 1 * SZ;
    float* bufV   = ws + 2 * SZ;
    float* bufAtt = ws + 3 * SZ;             // row-major [R, M]
    float* bufO1  = ws + 4 * SZ;
    float* bufO2  = ws + 5 * SZ;
    float* bufFF  = ws;                      // 2*SZ, reuses bufQ+bufK (free by then)

    dim3 blk(256);
    dim3 g16(16, 64);                        // N=1024: 16 x 64 tiles
    dim3 g32(32, 64);                        // N=2048
    dim3 ga(32, 32);                         // attention: 32 q-tiles x (B*H)

    // ---- masked self-attention ----
    gemm_k<1,1,0><<<g16, blk, 0, stream>>>(input, Wq1, bq1, bufQ, R_, M_, M_);
    gemm_k<1,1,0><<<g16, blk, 0, stream>>>(input, Wk1, bk1, bufK, R_, M_, M_);
    gemm_k<1,1,0><<<g16, blk, 0, stream>>>(input, Wv1, bv1, bufV, R_, M_, M_);
    attn_k<1><<<ga, blk, 0, stream>>>(bufQ, bufK, bufV, bufAtt, S_);
    gemm_k<0,0,0><<<g16, blk, 0, stream>>>(bufAtt, Wo1, bo1, bufQ, R_, M_, M_);
    ln_k<<<dim3(R_), blk, 0, stream>>>(bufQ, input, ln1g, ln1b, bufO1);

    // ---- cross-attention ----
    gemm_k<1,1,0><<<g16, blk, 0, stream>>>(bufO1, Wq2, bq2, bufQ, R_, M_, M_);
    gemm_k<1,1,0><<<g16, blk, 0, stream>>>(enc,   Wk2, bk2, bufK, R_, M_, M_);
    gemm_k<1,1,0><<<g16, blk, 0, stream>>>(enc,   Wv2, bv2, bufV, R_, M_, M_);
    attn_k<0><<<ga, blk, 0, stream>>>(bufQ, bufK, bufV, bufAtt, S_);
    gemm_k<0,0,0><<<g16, blk, 0, stream>>>(bufAtt, Wo2, bo2, bufK, R_, M_, M_);
    ln_k<<<dim3(R_), blk, 0, stream>>>(bufK, bufO1, ln2g, ln2b, bufO2);

    // ---- FFN ----
    gemm_k<0,0,1><<<g32, blk, 0, stream>>>(bufO2, Wf1, bf1, bufFF, R_, 2 * M_, M_);
    gemm_k<0,0,0><<<g16, blk, 0, stream>>>(bufFF, Wf2, bf2, bufV, R_, M_, 2 * M_);
    ln_k<<<dim3(R_), blk, 0, stream>>>(bufV, bufO2, ln3g, ln3b, out);
}

// Round 3
// 459.280 us; speedup vs baseline: 6.2366x; 6.2366x over previous
//
#include <hip/hip_runtime.h>
#include <math.h>

#define B_ 2
#define S_ 2048
#define M_ 1024
#define H_ 16
#define D_ 64
#define R_ (B_*S_)          // 4096 rows

typedef __attribute__((ext_vector_type(8))) short short8v;   // 8 bf16 = 4 VGPR
typedef __attribute__((ext_vector_type(4))) float float4v;

__device__ __forceinline__ float4 ld4(const float* p) {
    return *(const float4* __restrict__)p;
}

__device__ __forceinline__ ushort f2bf(float f) {            // RNE
    union { float f; unsigned u; } x; x.f = f;
    unsigned u = x.u + 0x7fffu + ((x.u >> 16) & 1u);
    return (ushort)(u >> 16);
}
__device__ __forceinline__ float bf2f(ushort s) {
    union { unsigned u; float f; } x; x.u = ((unsigned)s) << 16; return x.f;
}
__device__ __forceinline__ unsigned cvtpk(float lo, float hi) {
    unsigned r;
    asm("v_cvt_pk_bf16_f32 %0, %1, %2" : "=v"(r) : "v"(lo), "v"(hi));
    return r;
}
__device__ __forceinline__ float4v mfma16(short8v a, short8v b, float4v c) {
    return __builtin_amdgcn_mfma_f32_16x16x32_bf16(a, b, c, 0, 0, 0);
}
__device__ __forceinline__ void glds16(const void* g, void* l) {
    __builtin_amdgcn_global_load_lds(
        (const __attribute__((address_space(1))) void*)g,
        (__attribute__((address_space(3))) void*)l, 16, 0, 0);
}

// ---------------------------------------------------------------------------
// prep kernels
// ---------------------------------------------------------------------------
__global__ __launch_bounds__(256) void cast_k(const float* __restrict__ in,
                                              ushort* __restrict__ out) {
    size_t i = (size_t)blockIdx.x * blockDim.x + threadIdx.x;  // one float4
    float4 v = ld4(in + i * 4);
    ushort4 o = { f2bf(v.x), f2bf(v.y), f2bf(v.z), f2bf(v.w) };
    *(ushort4*)&out[i * 4] = o;
}

__global__ void copyf_k(const float* __restrict__ in, float* __restrict__ out, int n) {
    int i = blockIdx.x * 256 + threadIdx.x;
    if (i < n) out[i] = in[i];
}

// fp32 [z][K][N] -> bf16 [z-mapped][N][K]   (weight transpose-cast)
__global__ __launch_bounds__(256) void wtrans_k(const float* __restrict__ in,
                                                ushort* __restrict__ out,
                                                int K, int N, int outBatchStride) {
    __shared__ float t[32][33];
    const int z = blockIdx.z;
    const float* ib = in + (size_t)z * K * N;
    ushort* ob = out + (size_t)z * outBatchStride;
    const int k0 = blockIdx.y * 32, n0 = blockIdx.x * 32;
    const int tx = threadIdx.x & 31, ty = threadIdx.x >> 5;   // ty 0..7
    #pragma unroll
    for (int i = 0; i < 4; ++i)
        t[ty + i * 8][tx] = ib[(size_t)(k0 + ty + i * 8) * N + n0 + tx];
    __syncthreads();
    #pragma unroll
    for (int i = 0; i < 4; ++i)
        ob[(size_t)(n0 + ty + i * 8) * K + k0 + tx] = f2bf(t[tx][ty + i * 8]);
}

// bf16 [BH][S][64] -> [BH][64][S]   (V transpose for attention B-operand)
__global__ __launch_bounds__(256) void vtrans_k(const ushort* __restrict__ in,
                                                ushort* __restrict__ out) {
    __shared__ ushort t[32][36];
    const int bh = blockIdx.z;
    const int s0 = blockIdx.y * 32, d0 = blockIdx.x * 32;
    const int tx = threadIdx.x & 31, ty = threadIdx.x >> 5;
    #pragma unroll
    for (int i = 0; i < 4; ++i)
        t[ty + i * 8][tx] = in[((size_t)bh * S_ + s0 + ty + i * 8) * D_ + d0 + tx];
    __syncthreads();
    #pragma unroll
    for (int i = 0; i < 4; ++i)
        out[((size_t)bh * D_ + d0 + ty + i * 8) * S_ + s0 + tx] = t[tx][ty + i * 8];
}

// ---------------------------------------------------------------------------
// bf16 MFMA GEMM, 128x128 tile, BK=32, 256 thr (4 waves 2x2), m97 structure.
// A: bf16 [4096][K] row-major. Bt: bf16 [N][K] (k-contiguous). bias fp32 [N].
// OUTMODE: 0 = fp32 row-major, 1 = bf16 row-major, 2 = bf16 [mat][B][H][S][D]
// ---------------------------------------------------------------------------
template<int OUTMODE, int ACT>
__global__ __launch_bounds__(256) void gemm_bf16_k(
    const ushort* __restrict__ A, const ushort* __restrict__ Bt,
    const float* __restrict__ bias, void* __restrict__ C, int N, int K)
{
    __shared__ __align__(16) ushort At[128 * 32];
    __shared__ __align__(16) ushort Bts[128 * 32];
    const int tid = threadIdx.x, lane = tid & 63, w = tid >> 6;
    const int wm = w >> 1, wn = w & 1;
    const int q = lane & 15, g = lane >> 4;
    const int m0 = blockIdx.y * 128, n0 = blockIdx.x * 128;

    float4v acc[4][4];
    #pragma unroll
    for (int i = 0; i < 4; ++i)
        #pragma unroll
        for (int j = 0; j < 4; ++j) acc[i][j] = (float4v){0.f, 0.f, 0.f, 0.f};

    for (int k0 = 0; k0 < K; k0 += 32) {
        #pragma unroll
        for (int t = 0; t < 2; ++t) {
            const int cb = (w * 2 + t) * 64;
            const int c = cb + lane;
            const int row = c >> 2, kc = c & 3;
            glds16(&A [(size_t)(m0 + row) * K + k0 + kc * 8], &At [cb * 8]);
            glds16(&Bt[(size_t)(n0 + row) * K + k0 + kc * 8], &Bts[cb * 8]);
        }
        __syncthreads();
        short8v af[4], bf[4];
        #pragma unroll
        for (int i = 0; i < 4; ++i) {
            af[i] = *(const short8v*)&At [(wm * 64 + i * 16 + q) * 32 + g * 8];
            bf[i] = *(const short8v*)&Bts[(wn * 64 + i * 16 + q) * 32 + g * 8];
        }
        #pragma unroll
        for (int i = 0; i < 4; ++i)
            #pragma unroll
            for (int j = 0; j < 4; ++j)
                acc[i][j] = mfma16(af[i], bf[j], acc[i][j]);
        __syncthreads();
    }

    float bcol[4];
    #pragma unroll
    for (int j = 0; j < 4; ++j) bcol[j] = bias[n0 + wn * 64 + j * 16 + q];

    #pragma unroll
    for (int i = 0; i < 4; ++i) {
        #pragma unroll
        for (int j = 0; j < 4; ++j) {
            const int colg = n0 + wn * 64 + j * 16 + q;
            #pragma unroll
            for (int r = 0; r < 4; ++r) {
                const int rowg = m0 + wm * 64 + i * 16 + g * 4 + r;
                float v = acc[i][j][r] + bcol[j];
                if (ACT) v = fmaxf(v, 0.f);
                if (OUTMODE == 0) {
                    ((float*)C)[(size_t)rowg * N + colg] = v;
                } else if (OUTMODE == 1) {
                    ((ushort*)C)[(size_t)rowg * N + colg] = f2bf(v);
                } else {
                    const int mat = colg >> 10, h = (colg >> 6) & 15, d = colg & 63;
                    const int bb = rowg >> 11, s = rowg & 2047;
                    ((ushort*)C)[((((size_t)(mat * B_ + bb) * H_ + h) * S_) + s) * D_ + d] = f2bf(v);
                }
            }
        }
    }
}

// ---------------------------------------------------------------------------
// Flash attention, bf16 MFMA, swapped formulation.
// Q,K: bf16 [BH][S][64]; VT: bf16 [BH][64][S]; O: bf16 [R][1024] head-concat.
// Block: 128 q-rows, 4 waves (32 q each, 2 halves of 16). KV tiles of 64.
// P^T handoff through a per-wave LDS buffer (replaces the R2 shuffle repack).
// ---------------------------------------------------------------------------
template<int CAUSAL>
__global__ __launch_bounds__(256) void fattn_k(
    const ushort* __restrict__ Qg, const ushort* __restrict__ Kg,
    const ushort* __restrict__ VTg, ushort* __restrict__ Og, int Skv)
{
    __shared__ __align__(16) ushort Kt[64 * 64];
    __shared__ __align__(16) ushort Vt[64 * 64];
    __shared__ __align__(16) ushort Pt[4][32][72];   // per-wave P^T: [q_local][kv], +8 pad
    __shared__ __align__(16) ushort Ot[128 * 64];
    const int tid = threadIdx.x, lane = tid & 63, w = tid >> 6;
    const int g = lane >> 4, q = lane & 15;
    const int qb = CAUSAL ? ((int)gridDim.x - 1 - (int)blockIdx.x) : (int)blockIdx.x;
    const int bh = blockIdx.y;
    const int q0b = qb * 128;
    const int q0w = q0b + w * 32;

    short8v qf[2][2];
    #pragma unroll
    for (int h2 = 0; h2 < 2; ++h2)
        #pragma unroll
        for (int kf = 0; kf < 2; ++kf)
            qf[h2][kf] = *(const short8v*)&Qg[((size_t)bh * S_ + q0w + h2 * 16 + q) * 64 + kf * 32 + g * 8];

    float4v oacc[2][4];
    #pragma unroll
    for (int h2 = 0; h2 < 2; ++h2)
        #pragma unroll
        for (int d = 0; d < 4; ++d) oacc[h2][d] = (float4v){0.f, 0.f, 0.f, 0.f};
    float m_[2] = {-1e30f, -1e30f}, l_[2] = {0.f, 0.f};

    const int ktiles = CAUSAL ? (2 * qb + 2) : (Skv >> 6);

    for (int kt = 0; kt < ktiles; ++kt) {
        const int kv0 = kt * 64;
        #pragma unroll
        for (int t = 0; t < 2; ++t) {
            const int cb = (w * 2 + t) * 64;
            const int c = cb + lane;
            const int row = c >> 3, ch = c & 7, sc = ch ^ (row & 7);
            glds16(&Kg [((size_t)bh * Skv + kv0 + row) * 64 + sc * 8], &Kt[cb * 8]);
            glds16(&VTg[((size_t)bh * 64 + row) * Skv + kv0 + sc * 8], &Vt[cb * 8]);
        }
        __syncthreads();

        // S^T = K . Q^T   (rows kv, cols q)
        float4v st[2][4];
        #pragma unroll
        for (int h2 = 0; h2 < 2; ++h2)
            #pragma unroll
            for (int kvf = 0; kvf < 4; ++kvf) st[h2][kvf] = (float4v){0.f, 0.f, 0.f, 0.f};
        #pragma unroll
        for (int kvf = 0; kvf < 4; ++kvf) {
            const int kvr = kvf * 16 + q;
            #pragma unroll
            for (int kf = 0; kf < 2; ++kf) {
                short8v kfr = *(const short8v*)&Kt[kvr * 64 + (((kf * 4 + g) ^ (kvr & 7)) * 8)];
                #pragma unroll
                for (int h2 = 0; h2 < 2; ++h2)
                    st[h2][kvf] = mfma16(kfr, qf[h2][kf], st[h2][kvf]);
            }
        }

        // online softmax per q-half; write P^T rows to per-wave LDS
        #pragma unroll
        for (int h2 = 0; h2 < 2; ++h2) {
            const int qg_ = q0w + h2 * 16 + q;
            float mx = -1e30f;
            #pragma unroll
            for (int kvf = 0; kvf < 4; ++kvf)
                #pragma unroll
                for (int r = 0; r < 4; ++r) {
                    float s = st[h2][kvf][r] * 0.125f;
                    if (CAUSAL && (kv0 + kvf * 16 + g * 4 + r > qg_)) s = -1e9f;
                    st[h2][kvf][r] = s;
                    mx = fmaxf(mx, s);
                }
            mx = fmaxf(mx, __shfl_xor(mx, 16));
            mx = fmaxf(mx, __shfl_xor(mx, 32));
            const float nm = fmaxf(m_[h2], mx);
            const float f = __expf(m_[h2] - nm);
            float ls = 0.f;
            #pragma unroll
            for (int kvf = 0; kvf < 4; ++kvf)
                #pragma unroll
                for (int r = 0; r < 4; ++r) {
                    float p = __expf(st[h2][kvf][r] - nm);
                    st[h2][kvf][r] = p;
                    ls += p;
                }
            ls += __shfl_xor(ls, 16);
            ls += __shfl_xor(ls, 32);
            l_[h2] = l_[h2] * f + ls;
            m_[h2] = nm;
            #pragma unroll
            for (int d = 0; d < 4; ++d) oacc[h2][d] = oacc[h2][d] * f;

            // lane (q,g) owns P[q][kv0 + kvf*16 + g*4 + 0..3]; store bf16 pairs
            #pragma unroll
            for (int kvf = 0; kvf < 4; ++kvf) {
                uint2 pv;
                pv.x = cvtpk(st[h2][kvf][0], st[h2][kvf][1]);
                pv.y = cvtpk(st[h2][kvf][2], st[h2][kvf][3]);
                *(uint2*)&Pt[w][h2 * 16 + q][kvf * 16 + g * 4] = pv;
            }
        }

        // O^T += V^T . P^T   (B-frag read straight from Pt)
        #pragma unroll
        for (int df = 0; df < 4; ++df) {
            const int d = df * 16 + q;
            #pragma unroll
            for (int kf = 0; kf < 2; ++kf) {
                short8v vfr = *(const short8v*)&Vt[d * 64 + (((kf * 4 + g) ^ (d & 7)) * 8)];
                #pragma unroll
                for (int h2 = 0; h2 < 2; ++h2) {
                    short8v pf = *(const short8v*)&Pt[w][h2 * 16 + q][kf * 32 + g * 8];
                    oacc[h2][df] = mfma16(vfr, pf, oacc[h2][df]);
                }
            }
        }
        __syncthreads();
    }

    // normalize + stage O (swizzled) in LDS, then coalesced global store
    #pragma unroll
    for (int h2 = 0; h2 < 2; ++h2) {
        const float inv = 1.f / l_[h2];
        const int qr = w * 32 + h2 * 16 + q;
        #pragma unroll
        for (int df = 0; df < 4; ++df)
            #pragma unroll
            for (int rp = 0; rp < 2; ++rp) {
                unsigned pkd = cvtpk(oacc[h2][df][2 * rp] * inv, oacc[h2][df][2 * rp + 1] * inv);
                const int d = df * 16 + g * 4 + 2 * rp;
                const int ch = d >> 3;
                const int within = (d * 2) & 15;
                *(unsigned*)((char*)Ot + qr * 128 + (((ch ^ (qr & 7))) << 4) + within) = pkd;
            }
    }
    __syncthreads();
    const int b = bh >> 4, h = bh & 15;
    #pragma unroll
    for (int t = 0; t < 4; ++t) {
        const int c = t * 256 + tid;
        const int qrow = c >> 3, ch = c & 7;
        short8v v = *(const short8v*)((char*)Ot + qrow * 128 + (((ch ^ (qrow & 7))) << 4));
        *(short8v*)&Og[((size_t)(b * S_ + q0b + qrow)) * M_ + h * 64 + ch * 8] = v;
    }
}

// ---------------------------------------------------------------------------
// Fused residual-add + LayerNorm. X bf16, residual fp32; emits fp32 (+bf16).
// ---------------------------------------------------------------------------
template<int EMITB>
__global__ __launch_bounds__(256) void ln_k(
    const ushort* __restrict__ X, const float* __restrict__ Rz,
    const float* __restrict__ g, const float* __restrict__ be,
    float* __restrict__ outf, ushort* __restrict__ outb)
{
    __shared__ float red[8];
    const int row = blockIdx.x, tid = threadIdx.x;
    const int lane = tid & 63, w = tid >> 6;

    ushort4 xu = *(const ushort4*)&X[(size_t)row * M_ + tid * 4];
    float4 rr = ld4(Rz + (size_t)row * M_ + tid * 4);
    float4 x = make_float4(bf2f(xu.x) + rr.x, bf2f(xu.y) + rr.y,
                           bf2f(xu.z) + rr.z, bf2f(xu.w) + rr.w);

    float sm = x.x + x.y + x.z + x.w;
    #pragma unroll
    for (int off = 1; off < 64; off <<= 1) sm += __shfl_xor(sm, off);
    if (lane == 0) red[w] = sm;
    __syncthreads();
    const float mean = (red[0] + red[1] + red[2] + red[3]) * (1.f / M_);

    x.x -= mean; x.y -= mean; x.z -= mean; x.w -= mean;
    float vs = x.x * x.x + x.y * x.y + x.z * x.z + x.w * x.w;
    #pragma unroll
    for (int off = 1; off < 64; off <<= 1) vs += __shfl_xor(vs, off);
    if (lane == 0) red[4 + w] = vs;
    __syncthreads();
    const float var = (red[4] + red[5] + red[6] + red[7]) * (1.f / M_);
    const float rs = rsqrtf(var + 1e-5f);

    float4 gg = ld4(g + tid * 4), bb = ld4(be + tid * 4);
    float4 y = make_float4(x.x * rs * gg.x + bb.x, x.y * rs * gg.y + bb.y,
                           x.z * rs * gg.z + bb.z, x.w * rs * gg.w + bb.w);
    *(float4*)(outf + (size_t)row * M_ + tid * 4) = y;
    if (EMITB) {
        ushort4 ob = { f2bf(y.x), f2bf(y.y), f2bf(y.z), f2bf(y.w) };
        *(ushort4*)&outb[(size_t)row * M_ + tid * 4] = ob;
    }
}

// ---------------------------------------------------------------------------
extern "C" void kernel_launch(void* const* d_in, const int* in_sizes, int n_in,
                              void* d_out, int out_size, void* d_ws, size_t ws_size,
                              hipStream_t stream)
{
    const float* input = (const float*)d_in[0];
    const float* enc   = (const float*)d_in[1];
    const float* Wq1 = (const float*)d_in[2];  const float* bq1 = (const float*)d_in[3];
    const float* Wk1 = (const float*)d_in[4];  const float* bk1 = (const float*)d_in[5];
    const float* Wv1 = (const float*)d_in[6];  const float* bv1 = (const float*)d_in[7];
    const float* Wo1 = (const float*)d_in[8];  const float* bo1 = (const float*)d_in[9];
    const float* ln1g = (const float*)d_in[10]; const float* ln1b = (const float*)d_in[11];
    const float* Wq2 = (const float*)d_in[12]; const float* bq2 = (const float*)d_in[13];
    const float* Wk2 = (const float*)d_in[14]; const float* bk2 = (const float*)d_in[15];
    const float* Wv2 = (const float*)d_in[16]; const float* bv2 = (const float*)d_in[17];
    const float* Wo2 = (const float*)d_in[18]; const float* bo2 = (const float*)d_in[19];
    const float* ln2g = (const float*)d_in[20]; const float* ln2b = (const float*)d_in[21];
    const float* Wf1 = (const float*)d_in[22]; const float* bf1 = (const float*)d_in[23];
    const float* Wf2 = (const float*)d_in[24]; const float* bf2 = (const float*)d_in[25];
    const float* ln3g = (const float*)d_in[26]; const float* ln3b = (const float*)d_in[27];

    char* W = (char*)d_ws;
    #define OFS(mb) ((void*)(W + (size_t)(mb) * 1024 * 1024))
    ushort* x0b    = (ushort*)OFS(0);
    ushort* encb   = (ushort*)OFS(8);
    ushort* WqkvT1 = (ushort*)OFS(16);
    ushort* Wo1T   = (ushort*)OFS(22);
    ushort* Wq2T   = (ushort*)OFS(24);
    ushort* WkvT2  = (ushort*)OFS(26);
    ushort* Wo2T   = (ushort*)OFS(30);
    ushort* Wf1T   = (ushort*)OFS(32);
    ushort* Wf2T   = (ushort*)OFS(36);
    float*  biasQKV1 = (float*)OFS(40);
    float*  biasKV2  = (float*)((char*)OFS(40) + 16384);
    ushort* QKV1   = (ushort*)OFS(41);   // [3][B][H][S][D]
    ushort* VT1    = (ushort*)OFS(65);
    ushort* att1b  = (ushort*)OFS(73);
    ushort* o1b    = (ushort*)OFS(81);
    float*  out1f  = (float*)OFS(41);
    ushort* out1b  = (ushort*)OFS(57);
    ushort* Q2     = (ushort*)OFS(65);
    ushort* KV2    = (ushort*)OFS(73);   // [2][B][H][S][D]
    ushort* VT2    = (ushort*)OFS(0);
    ushort* att2b  = (ushort*)OFS(8);
    ushort* o2b    = (ushort*)OFS(65);
    float*  out2f  = (float*)OFS(73);
    ushort* out2b  = (ushort*)OFS(0);
    ushort* ff1b   = (ushort*)OFS(41);
    ushort* ff2b   = (ushort*)OFS(57);
    float*  out    = (float*)d_out;
    const size_t MAT = (size_t)B_ * H_ * S_ * D_;   // 4 Mi elements

    dim3 blk(256);

    // ---- prep: casts, weight transposes, bias packs ----
    cast_k<<<4096, blk, 0, stream>>>(input, x0b);
    cast_k<<<4096, blk, 0, stream>>>(enc, encb);
    wtrans_k<<<dim3(2, 32, 16), blk, 0, stream>>>(Wq1, WqkvT1,               1024, 64, 64 * 1024);
    wtrans_k<<<dim3(2, 32, 16), blk, 0, stream>>>(Wk1, WqkvT1 + 1024 * 1024, 1024, 64, 64 * 1024);
    wtrans_k<<<dim3(2, 32, 16), blk, 0, stream>>>(Wv1, WqkvT1 + 2048 * 1024, 1024, 64, 64 * 1024);
    wtrans_k<<<dim3(32, 32, 1), blk, 0, stream>>>(Wo1, Wo1T, 1024, 1024, 0);
    wtrans_k<<<dim3(2, 32, 16), blk, 0, stream>>>(Wq2, Wq2T, 1024, 64, 64 * 1024);
    wtrans_k<<<dim3(2, 32, 16), blk, 0, stream>>>(Wk2, WkvT2,               1024, 64, 64 * 1024);
    wtrans_k<<<dim3(2, 32, 16), blk, 0, stream>>>(Wv2, WkvT2 + 1024 * 1024, 1024, 64, 64 * 1024);
    wtrans_k<<<dim3(32, 32, 1), blk, 0, stream>>>(Wo2, Wo2T, 1024, 1024, 0);
    wtrans_k<<<dim3(64, 32, 1), blk, 0, stream>>>(Wf1, Wf1T, 1024, 2048, 0);
    wtrans_k<<<dim3(32, 64, 1), blk, 0, stream>>>(Wf2, Wf2T, 2048, 1024, 0);
    copyf_k<<<4, blk, 0, stream>>>(bq1, biasQKV1,        1024);
    copyf_k<<<4, blk, 0, stream>>>(bk1, biasQKV1 + 1024, 1024);
    copyf_k<<<4, blk, 0, stream>>>(bv1, biasQKV1 + 2048, 1024);
    copyf_k<<<4, blk, 0, stream>>>(bk2, biasKV2,         1024);
    copyf_k<<<4, blk, 0, stream>>>(bv2, biasKV2 + 1024,  1024);

    // ---- masked self-attention ----
    gemm_bf16_k<2, 0><<<dim3(24, 32), blk, 0, stream>>>(x0b, WqkvT1, biasQKV1, QKV1, 3072, 1024);
    vtrans_k<<<dim3(2, 64, 32), blk, 0, stream>>>(QKV1 + 2 * MAT, VT1);
    fattn_k<1><<<dim3(16, 32), blk, 0, stream>>>(QKV1, QKV1 + MAT, VT1, att1b, S_);
    gemm_bf16_k<1, 0><<<dim3(8, 32), blk, 0, stream>>>(att1b, Wo1T, bo1, o1b, 1024, 1024);
    ln_k<1><<<dim3(R_), blk, 0, stream>>>(o1b, input, ln1g, ln1b, out1f, out1b);

    // ---- cross-attention ----
    gemm_bf16_k<2, 0><<<dim3(8, 32), blk, 0, stream>>>(out1b, Wq2T, bq2, Q2, 1024, 1024);
    gemm_bf16_k<2, 0><<<dim3(16, 32), blk, 0, stream>>>(encb, WkvT2, biasKV2, KV2, 2048, 1024);
    vtrans_k<<<dim3(2, 64, 32), blk, 0, stream>>>(KV2 + MAT, VT2);
    fattn_k<0><<<dim3(16, 32), blk, 0, stream>>>(Q2, KV2, VT2, att2b, S_);
    gemm_bf16_k<1, 0><<<dim3(8, 32), blk, 0, stream>>>(att2b, Wo2T, bo2, o2b, 1024, 1024);
    ln_k<1><<<dim3(R_), blk, 0, stream>>>(o2b, out1f, ln2g, ln2b, out2f, out2b);

    // ---- FFN ----
    gemm_bf16_k<1, 1><<<dim3(16, 32), blk, 0, stream>>>(out2b, Wf1T, bf1, ff1b, 2048, 1024);
    gemm_bf16_k<1, 0><<<dim3(8, 32), blk, 0, stream>>>(ff1b, Wf2T, bf2, ff2b, 1024, 2048);
    ln_k<0><<<dim3(R_), blk, 0, stream>>>(ff2b, out2f, ln3g, ln3b, out, nullptr);
    #undef OFS
}

// Round 4
// 456.700 us; speedup vs baseline: 6.2719x; 1.0057x over previous
//
#include <hip/hip_runtime.h>
#include <math.h>

#define B_ 2
#define S_ 2048
#define M_ 1024
#define H_ 16
#define D_ 64
#define R_ (B_*S_)          // 4096 rows

typedef __attribute__((ext_vector_type(8))) short short8v;   // 8 bf16 = 4 VGPR
typedef __attribute__((ext_vector_type(4))) float float4v;

__device__ __forceinline__ float4 ld4(const float* p) {
    return *(const float4* __restrict__)p;
}

__device__ __forceinline__ ushort f2bf(float f) {            // RNE
    union { float f; unsigned u; } x; x.f = f;
    unsigned u = x.u + 0x7fffu + ((x.u >> 16) & 1u);
    return (ushort)(u >> 16);
}
__device__ __forceinline__ float bf2f(ushort s) {
    union { unsigned u; float f; } x; x.u = ((unsigned)s) << 16; return x.f;
}
__device__ __forceinline__ unsigned cvtpk(float lo, float hi) {
    unsigned r;
    asm("v_cvt_pk_bf16_f32 %0, %1, %2" : "=v"(r) : "v"(lo), "v"(hi));
    return r;
}
__device__ __forceinline__ float4v mfma16(short8v a, short8v b, float4v c) {
    return __builtin_amdgcn_mfma_f32_16x16x32_bf16(a, b, c, 0, 0, 0);
}
__device__ __forceinline__ void glds16(const void* g, void* l) {
    __builtin_amdgcn_global_load_lds(
        (const __attribute__((address_space(1))) void*)g,
        (__attribute__((address_space(3))) void*)l, 16, 0, 0);
}

// ---------------------------------------------------------------------------
// prep kernels
// ---------------------------------------------------------------------------
__global__ __launch_bounds__(256) void cast_k(const float* __restrict__ in,
                                              ushort* __restrict__ out) {
    size_t i = (size_t)blockIdx.x * blockDim.x + threadIdx.x;  // one float4
    float4 v = ld4(in + i * 4);
    ushort4 o = { f2bf(v.x), f2bf(v.y), f2bf(v.z), f2bf(v.w) };
    *(ushort4*)&out[i * 4] = o;
}

__global__ void copyf_k(const float* __restrict__ in, float* __restrict__ out, int n) {
    int i = blockIdx.x * 256 + threadIdx.x;
    if (i < n) out[i] = in[i];
}

// fp32 [z][K][N] -> bf16 [z-mapped][N][K]   (weight transpose-cast)
__global__ __launch_bounds__(256) void wtrans_k(const float* __restrict__ in,
                                                ushort* __restrict__ out,
                                                int K, int N, int outBatchStride) {
    __shared__ float t[32][33];
    const int z = blockIdx.z;
    const float* ib = in + (size_t)z * K * N;
    ushort* ob = out + (size_t)z * outBatchStride;
    const int k0 = blockIdx.y * 32, n0 = blockIdx.x * 32;
    const int tx = threadIdx.x & 31, ty = threadIdx.x >> 5;   // ty 0..7
    #pragma unroll
    for (int i = 0; i < 4; ++i)
        t[ty + i * 8][tx] = ib[(size_t)(k0 + ty + i * 8) * N + n0 + tx];
    __syncthreads();
    #pragma unroll
    for (int i = 0; i < 4; ++i)
        ob[(size_t)(n0 + ty + i * 8) * K + k0 + tx] = f2bf(t[tx][ty + i * 8]);
}

// bf16 [BH][S][64] -> [BH][64][S]   (V transpose for attention B-operand)
__global__ __launch_bounds__(256) void vtrans_k(const ushort* __restrict__ in,
                                                ushort* __restrict__ out) {
    __shared__ ushort t[32][36];
    const int bh = blockIdx.z;
    const int s0 = blockIdx.y * 32, d0 = blockIdx.x * 32;
    const int tx = threadIdx.x & 31, ty = threadIdx.x >> 5;
    #pragma unroll
    for (int i = 0; i < 4; ++i)
        t[ty + i * 8][tx] = in[((size_t)bh * S_ + s0 + ty + i * 8) * D_ + d0 + tx];
    __syncthreads();
    #pragma unroll
    for (int i = 0; i < 4; ++i)
        out[((size_t)bh * D_ + d0 + ty + i * 8) * S_ + s0 + tx] = t[tx][ty + i * 8];
}

// ---------------------------------------------------------------------------
// bf16 MFMA GEMM, 128x128 tile, BK=32, 256 thr (4 waves 2x2), m97 structure.
// A: bf16 [4096][K] row-major. Bt: bf16 [N][K] (k-contiguous). bias fp32 [N].
// OUTMODE: 0 = fp32 row-major, 1 = bf16 row-major, 2 = bf16 [mat][B][H][S][D]
// ---------------------------------------------------------------------------
template<int OUTMODE, int ACT>
__global__ __launch_bounds__(256) void gemm_bf16_k(
    const ushort* __restrict__ A, const ushort* __restrict__ Bt,
    const float* __restrict__ bias, void* __restrict__ C, int N, int K)
{
    __shared__ __align__(16) ushort At[128 * 32];
    __shared__ __align__(16) ushort Bts[128 * 32];
    const int tid = threadIdx.x, lane = tid & 63, w = tid >> 6;
    const int wm = w >> 1, wn = w & 1;
    const int q = lane & 15, g = lane >> 4;
    const int m0 = blockIdx.y * 128, n0 = blockIdx.x * 128;

    float4v acc[4][4];
    #pragma unroll
    for (int i = 0; i < 4; ++i)
        #pragma unroll
        for (int j = 0; j < 4; ++j) acc[i][j] = (float4v){0.f, 0.f, 0.f, 0.f};

    for (int k0 = 0; k0 < K; k0 += 32) {
        #pragma unroll
        for (int t = 0; t < 2; ++t) {
            const int cb = (w * 2 + t) * 64;
            const int c = cb + lane;
            const int row = c >> 2, kc = c & 3;
            glds16(&A [(size_t)(m0 + row) * K + k0 + kc * 8], &At [cb * 8]);
            glds16(&Bt[(size_t)(n0 + row) * K + k0 + kc * 8], &Bts[cb * 8]);
        }
        __syncthreads();
        short8v af[4], bf[4];
        #pragma unroll
        for (int i = 0; i < 4; ++i) {
            af[i] = *(const short8v*)&At [(wm * 64 + i * 16 + q) * 32 + g * 8];
            bf[i] = *(const short8v*)&Bts[(wn * 64 + i * 16 + q) * 32 + g * 8];
        }
        #pragma unroll
        for (int i = 0; i < 4; ++i)
            #pragma unroll
            for (int j = 0; j < 4; ++j)
                acc[i][j] = mfma16(af[i], bf[j], acc[i][j]);
        __syncthreads();
    }

    float bcol[4];
    #pragma unroll
    for (int j = 0; j < 4; ++j) bcol[j] = bias[n0 + wn * 64 + j * 16 + q];

    #pragma unroll
    for (int i = 0; i < 4; ++i) {
        #pragma unroll
        for (int j = 0; j < 4; ++j) {
            const int colg = n0 + wn * 64 + j * 16 + q;
            #pragma unroll
            for (int r = 0; r < 4; ++r) {
                const int rowg = m0 + wm * 64 + i * 16 + g * 4 + r;
                float v = acc[i][j][r] + bcol[j];
                if (ACT) v = fmaxf(v, 0.f);
                if (OUTMODE == 0) {
                    ((float*)C)[(size_t)rowg * N + colg] = v;
                } else if (OUTMODE == 1) {
                    ((ushort*)C)[(size_t)rowg * N + colg] = f2bf(v);
                } else {
                    const int mat = colg >> 10, h = (colg >> 6) & 15, d = colg & 63;
                    const int bb = rowg >> 11, s = rowg & 2047;
                    ((ushort*)C)[((((size_t)(mat * B_ + bb) * H_ + h) * S_) + s) * D_ + d] = f2bf(v);
                }
            }
        }
    }
}

// ---------------------------------------------------------------------------
// Flash attention, bf16 MFMA, swapped formulation. 8 waves x 16 q-rows (512 thr).
// Q,K: bf16 [BH][S][64]; VT: bf16 [BH][64][S]; O: bf16 [R][1024] head-concat.
// KV tiles of 64. Per-wave P^T rows live in POt (XOR chunk swizzle); the same
// region is reused as the Ot staging buffer after the KV loop (exact overlay:
// wave w's Pt rows == wave w's Ot rows). LDS total 32 KB -> 2 blk/CU x 8 waves.
// ---------------------------------------------------------------------------
template<int CAUSAL>
__global__ __launch_bounds__(512) void fattn_k(
    const ushort* __restrict__ Qg, const ushort* __restrict__ Kg,
    const ushort* __restrict__ VTg, ushort* __restrict__ Og, int Skv)
{
    __shared__ __align__(16) ushort Kt[64 * 64];      // 8 KB
    __shared__ __align__(16) ushort Vt[64 * 64];      // 8 KB
    __shared__ __align__(16) ushort POt[128 * 64];    // 16 KB: Pt in-loop, Ot after
    const int tid = threadIdx.x, lane = tid & 63, w = tid >> 6;   // w 0..7
    const int g = lane >> 4, q = lane & 15;
    const int qb = CAUSAL ? ((int)gridDim.x - 1 - (int)blockIdx.x) : (int)blockIdx.x;
    const int bh = blockIdx.y;
    const int q0b = qb * 128;
    const int q0w = q0b + w * 16;
    const int qr = w * 16 + q;                        // this lane's q row (block-local)
    const float SC = 0.18033688f;                     // 0.125 * log2(e)

    short8v qf[2];
    #pragma unroll
    for (int kf = 0; kf < 2; ++kf)
        qf[kf] = *(const short8v*)&Qg[((size_t)bh * S_ + q0w + q) * 64 + kf * 32 + g * 8];

    float4v oacc[4];
    #pragma unroll
    for (int d = 0; d < 4; ++d) oacc[d] = (float4v){0.f, 0.f, 0.f, 0.f};
    float m_ = -1e30f, l_ = 0.f;

    const int ktiles = CAUSAL ? (2 * qb + 2) : (Skv >> 6);

    for (int kt = 0; kt < ktiles; ++kt) {
        const int kv0 = kt * 64;
        {   // stage K and V^T tiles: 512 chunks each, one per thread
            const int c = w * 64 + lane;
            const int row = c >> 3, ch = c & 7, sc = ch ^ (row & 7);
            glds16(&Kg [((size_t)bh * Skv + kv0 + row) * 64 + sc * 8], &Kt[(size_t)(w * 64) * 8]);
            glds16(&VTg[((size_t)bh * 64 + row) * Skv + kv0 + sc * 8], &Vt[(size_t)(w * 64) * 8]);
        }
        __syncthreads();

        // S^T = K . Q^T   (rows kv, cols q)
        float4v st[4];
        #pragma unroll
        for (int kvf = 0; kvf < 4; ++kvf) st[kvf] = (float4v){0.f, 0.f, 0.f, 0.f};
        #pragma unroll
        for (int kvf = 0; kvf < 4; ++kvf) {
            const int kvr = kvf * 16 + q;
            #pragma unroll
            for (int kf = 0; kf < 2; ++kf) {
                short8v kfr = *(const short8v*)&Kt[kvr * 64 + (((kf * 4 + g) ^ (kvr & 7)) * 8)];
                st[kvf] = mfma16(kfr, qf[kf], st[kvf]);
            }
        }

        // online softmax (exp2 domain), then P^T rows to per-wave POt region
        {
            const int qg_ = q0w + q;
            float mx = -1e30f;
            #pragma unroll
            for (int kvf = 0; kvf < 4; ++kvf)
                #pragma unroll
                for (int r = 0; r < 4; ++r) {
                    float s = st[kvf][r] * SC;
                    if (CAUSAL && (kv0 + kvf * 16 + g * 4 + r > qg_)) s = -1e9f;
                    st[kvf][r] = s;
                    mx = fmaxf(mx, s);
                }
            mx = fmaxf(mx, __shfl_xor(mx, 16));
            mx = fmaxf(mx, __shfl_xor(mx, 32));
            const float nm = fmaxf(m_, mx);
            const float f = exp2f(m_ - nm);
            float ls = 0.f;
            #pragma unroll
            for (int kvf = 0; kvf < 4; ++kvf)
                #pragma unroll
                for (int r = 0; r < 4; ++r) {
                    float p = exp2f(st[kvf][r] - nm);
                    st[kvf][r] = p;
                    ls += p;
                }
            ls += __shfl_xor(ls, 16);
            ls += __shfl_xor(ls, 32);
            l_ = l_ * f + ls;
            m_ = nm;
            #pragma unroll
            for (int d = 0; d < 4; ++d) oacc[d] = oacc[d] * f;

            // lane (q,g) owns P[q][kv0 + kvf*16 + g*4 + 0..3]
            #pragma unroll
            for (int kvf = 0; kvf < 4; ++kvf) {
                uint2 pv;
                pv.x = cvtpk(st[kvf][0], st[kvf][1]);
                pv.y = cvtpk(st[kvf][2], st[kvf][3]);
                const int c = kvf * 2 + (g >> 1);
                *(uint2*)((char*)POt + qr * 128 + ((c ^ (q & 7)) << 4) + (g & 1) * 8) = pv;
            }
        }

        // O^T += V^T . P^T
        {
            short8v pf[2];
            #pragma unroll
            for (int kf = 0; kf < 2; ++kf)
                pf[kf] = *(const short8v*)((char*)POt + qr * 128 + (((kf * 4 + g) ^ (q & 7)) << 4));
            #pragma unroll
            for (int df = 0; df < 4; ++df) {
                const int d = df * 16 + q;
                #pragma unroll
                for (int kf = 0; kf < 2; ++kf) {
                    short8v vfr = *(const short8v*)&Vt[d * 64 + (((kf * 4 + g) ^ (d & 7)) * 8)];
                    oacc[df] = mfma16(vfr, pf[kf], oacc[df]);
                }
            }
        }
        __syncthreads();
    }

    // normalize + stage O into POt (own wave's rows; Pt dead), swizzled
    {
        const float inv = 1.f / l_;
        #pragma unroll
        for (int df = 0; df < 4; ++df)
            #pragma unroll
            for (int rp = 0; rp < 2; ++rp) {
                unsigned pkd = cvtpk(oacc[df][2 * rp] * inv, oacc[df][2 * rp + 1] * inv);
                const int d = df * 16 + g * 4 + 2 * rp;
                *(unsigned*)((char*)POt + qr * 128 + (((d >> 3) ^ (qr & 7)) << 4) + ((2 * d) & 15)) = pkd;
            }
    }
    __syncthreads();
    const int b = bh >> 4, h = bh & 15;
    #pragma unroll
    for (int t = 0; t < 2; ++t) {
        const int c = t * 512 + tid;
        const int qrow = c >> 3, ch = c & 7;
        short8v v = *(const short8v*)((char*)POt + qrow * 128 + ((ch ^ (qrow & 7)) << 4));
        *(short8v*)&Og[((size_t)(b * S_ + q0b + qrow)) * M_ + h * 64 + ch * 8] = v;
    }
}

// ---------------------------------------------------------------------------
// Fused residual-add + LayerNorm. X bf16, residual fp32; emits fp32 (+bf16).
// ---------------------------------------------------------------------------
template<int EMITB>
__global__ __launch_bounds__(256) void ln_k(
    const ushort* __restrict__ X, const float* __restrict__ Rz,
    const float* __restrict__ g, const float* __restrict__ be,
    float* __restrict__ outf, ushort* __restrict__ outb)
{
    __shared__ float red[8];
    const int row = blockIdx.x, tid = threadIdx.x;
    const int lane = tid & 63, w = tid >> 6;

    ushort4 xu = *(const ushort4*)&X[(size_t)row * M_ + tid * 4];
    float4 rr = ld4(Rz + (size_t)row * M_ + tid * 4);
    float4 x = make_float4(bf2f(xu.x) + rr.x, bf2f(xu.y) + rr.y,
                           bf2f(xu.z) + rr.z, bf2f(xu.w) + rr.w);

    float sm = x.x + x.y + x.z + x.w;
    #pragma unroll
    for (int off = 1; off < 64; off <<= 1) sm += __shfl_xor(sm, off);
    if (lane == 0) red[w] = sm;
    __syncthreads();
    const float mean = (red[0] + red[1] + red[2] + red[3]) * (1.f / M_);

    x.x -= mean; x.y -= mean; x.z -= mean; x.w -= mean;
    float vs = x.x * x.x + x.y * x.y + x.z * x.z + x.w * x.w;
    #pragma unroll
    for (int off = 1; off < 64; off <<= 1) vs += __shfl_xor(vs, off);
    if (lane == 0) red[4 + w] = vs;
    __syncthreads();
    const float var = (red[4] + red[5] + red[6] + red[7]) * (1.f / M_);
    const float rs = rsqrtf(var + 1e-5f);

    float4 gg = ld4(g + tid * 4), bb = ld4(be + tid * 4);
    float4 y = make_float4(x.x * rs * gg.x + bb.x, x.y * rs * gg.y + bb.y,
                           x.z * rs * gg.z + bb.z, x.w * rs * gg.w + bb.w);
    *(float4*)(outf + (size_t)row * M_ + tid * 4) = y;
    if (EMITB) {
        ushort4 ob = { f2bf(y.x), f2bf(y.y), f2bf(y.z), f2bf(y.w) };
        *(ushort4*)&outb[(size_t)row * M_ + tid * 4] = ob;
    }
}

// ---------------------------------------------------------------------------
extern "C" void kernel_launch(void* const* d_in, const int* in_sizes, int n_in,
                              void* d_out, int out_size, void* d_ws, size_t ws_size,
                              hipStream_t stream)
{
    const float* input = (const float*)d_in[0];
    const float* enc   = (const float*)d_in[1];
    const float* Wq1 = (const float*)d_in[2];  const float* bq1 = (const float*)d_in[3];
    const float* Wk1 = (const float*)d_in[4];  const float* bk1 = (const float*)d_in[5];
    const float* Wv1 = (const float*)d_in[6];  const float* bv1 = (const float*)d_in[7];
    const float* Wo1 = (const float*)d_in[8];  const float* bo1 = (const float*)d_in[9];
    const float* ln1g = (const float*)d_in[10]; const float* ln1b = (const float*)d_in[11];
    const float* Wq2 = (const float*)d_in[12]; const float* bq2 = (const float*)d_in[13];
    const float* Wk2 = (const float*)d_in[14]; const float* bk2 = (const float*)d_in[15];
    const float* Wv2 = (const float*)d_in[16]; const float* bv2 = (const float*)d_in[17];
    const float* Wo2 = (const float*)d_in[18]; const float* bo2 = (const float*)d_in[19];
    const float* ln2g = (const float*)d_in[20]; const float* ln2b = (const float*)d_in[21];
    const float* Wf1 = (const float*)d_in[22]; const float* bf1 = (const float*)d_in[23];
    const float* Wf2 = (const float*)d_in[24]; const float* bf2 = (const float*)d_in[25];
    const float* ln3g = (const float*)d_in[26]; const float* ln3b = (const float*)d_in[27];

    char* W = (char*)d_ws;
    #define OFS(mb) ((void*)(W + (size_t)(mb) * 1024 * 1024))
    ushort* x0b    = (ushort*)OFS(0);
    ushort* encb   = (ushort*)OFS(8);
    ushort* WqkvT1 = (ushort*)OFS(16);
    ushort* Wo1T   = (ushort*)OFS(22);
    ushort* Wq2T   = (ushort*)OFS(24);
    ushort* WkvT2  = (ushort*)OFS(26);
    ushort* Wo2T   = (ushort*)OFS(30);
    ushort* Wf1T   = (ushort*)OFS(32);
    ushort* Wf2T   = (ushort*)OFS(36);
    float*  biasQKV1 = (float*)OFS(40);
    float*  biasKV2  = (float*)((char*)OFS(40) + 16384);
    ushort* QKV1   = (ushort*)OFS(41);   // [3][B][H][S][D]
    ushort* VT1    = (ushort*)OFS(65);
    ushort* att1b  = (ushort*)OFS(73);
    ushort* o1b    = (ushort*)OFS(81);
    float*  out1f  = (float*)OFS(41);
    ushort* out1b  = (ushort*)OFS(57);
    ushort* Q2     = (ushort*)OFS(65);
    ushort* KV2    = (ushort*)OFS(73);   // [2][B][H][S][D]
    ushort* VT2    = (ushort*)OFS(0);
    ushort* att2b  = (ushort*)OFS(8);
    ushort* o2b    = (ushort*)OFS(65);
    float*  out2f  = (float*)OFS(73);
    ushort* out2b  = (ushort*)OFS(0);
    ushort* ff1b   = (ushort*)OFS(41);
    ushort* ff2b   = (ushort*)OFS(57);
    float*  out    = (float*)d_out;
    const size_t MAT = (size_t)B_ * H_ * S_ * D_;   // 4 Mi elements

    dim3 blk(256);
    dim3 blkA(512);

    // ---- prep: casts, weight transposes, bias packs ----
    cast_k<<<4096, blk, 0, stream>>>(input, x0b);
    cast_k<<<4096, blk, 0, stream>>>(enc, encb);
    wtrans_k<<<dim3(2, 32, 16), blk, 0, stream>>>(Wq1, WqkvT1,               1024, 64, 64 * 1024);
    wtrans_k<<<dim3(2, 32, 16), blk, 0, stream>>>(Wk1, WqkvT1 + 1024 * 1024, 1024, 64, 64 * 1024);
    wtrans_k<<<dim3(2, 32, 16), blk, 0, stream>>>(Wv1, WqkvT1 + 2048 * 1024, 1024, 64, 64 * 1024);
    wtrans_k<<<dim3(32, 32, 1), blk, 0, stream>>>(Wo1, Wo1T, 1024, 1024, 0);
    wtrans_k<<<dim3(2, 32, 16), blk, 0, stream>>>(Wq2, Wq2T, 1024, 64, 64 * 1024);
    wtrans_k<<<dim3(2, 32, 16), blk, 0, stream>>>(Wk2, WkvT2,               1024, 64, 64 * 1024);
    wtrans_k<<<dim3(2, 32, 16), blk, 0, stream>>>(Wv2, WkvT2 + 1024 * 1024, 1024, 64, 64 * 1024);
    wtrans_k<<<dim3(32, 32, 1), blk, 0, stream>>>(Wo2, Wo2T, 1024, 1024, 0);
    wtrans_k<<<dim3(64, 32, 1), blk, 0, stream>>>(Wf1, Wf1T, 1024, 2048, 0);
    wtrans_k<<<dim3(32, 64, 1), blk, 0, stream>>>(Wf2, Wf2T, 2048, 1024, 0);
    copyf_k<<<4, blk, 0, stream>>>(bq1, biasQKV1,        1024);
    copyf_k<<<4, blk, 0, stream>>>(bk1, biasQKV1 + 1024, 1024);
    copyf_k<<<4, blk, 0, stream>>>(bv1, biasQKV1 + 2048, 1024);
    copyf_k<<<4, blk, 0, stream>>>(bk2, biasKV2,         1024);
    copyf_k<<<4, blk, 0, stream>>>(bv2, biasKV2 + 1024,  1024);

    // ---- masked self-attention ----
    gemm_bf16_k<2, 0><<<dim3(24, 32), blk, 0, stream>>>(x0b, WqkvT1, biasQKV1, QKV1, 3072, 1024);
    vtrans_k<<<dim3(2, 64, 32), blk, 0, stream>>>(QKV1 + 2 * MAT, VT1);
    fattn_k<1><<<dim3(16, 32), blkA, 0, stream>>>(QKV1, QKV1 + MAT, VT1, att1b, S_);
    gemm_bf16_k<1, 0><<<dim3(8, 32), blk, 0, stream>>>(att1b, Wo1T, bo1, o1b, 1024, 1024);
    ln_k<1><<<dim3(R_), blk, 0, stream>>>(o1b, input, ln1g, ln1b, out1f, out1b);

    // ---- cross-attention ----
    gemm_bf16_k<2, 0><<<dim3(8, 32), blk, 0, stream>>>(out1b, Wq2T, bq2, Q2, 1024, 1024);
    gemm_bf16_k<2, 0><<<dim3(16, 32), blk, 0, stream>>>(encb, WkvT2, biasKV2, KV2, 2048, 1024);
    vtrans_k<<<dim3(2, 64, 32), blk, 0, stream>>>(KV2 + MAT, VT2);
    fattn_k<0><<<dim3(16, 32), blkA, 0, stream>>>(Q2, KV2, VT2, att2b, S_);
    gemm_bf16_k<1, 0><<<dim3(8, 32), blk, 0, stream>>>(att2b, Wo2T, bo2, o2b, 1024, 1024);
    ln_k<1><<<dim3(R_), blk, 0, stream>>>(o2b, out1f, ln2g, ln2b, out2f, out2b);

    // ---- FFN ----
    gemm_bf16_k<1, 1><<<dim3(16, 32), blk, 0, stream>>>(out2b, Wf1T, bf1, ff1b, 2048, 1024);
    gemm_bf16_k<1, 0><<<dim3(8, 32), blk, 0, stream>>>(ff1b, Wf2T, bf2, ff2b, 1024, 2048);
    ln_k<0><<<dim3(R_), blk, 0, stream>>>(ff2b, out2f, ln3g, ln3b, out, nullptr);
    #undef OFS
}

// Round 5
// 420.900 us; speedup vs baseline: 6.8053x; 1.0851x over previous
//
#include <hip/hip_runtime.h>
#include <math.h>

#define B_ 2
#define S_ 2048
#define M_ 1024
#define H_ 16
#define D_ 64
#define R_ (B_*S_)          // 4096 rows

typedef __attribute__((ext_vector_type(8))) short short8v;   // 8 bf16 = 4 VGPR
typedef __attribute__((ext_vector_type(4))) float float4v;

__device__ __forceinline__ float4 ld4(const float* p) {
    return *(const float4* __restrict__)p;
}

__device__ __forceinline__ ushort f2bf(float f) {            // RNE
    union { float f; unsigned u; } x; x.f = f;
    unsigned u = x.u + 0x7fffu + ((x.u >> 16) & 1u);
    return (ushort)(u >> 16);
}
__device__ __forceinline__ float bf2f(ushort s) {
    union { unsigned u; float f; } x; x.u = ((unsigned)s) << 16; return x.f;
}
__device__ __forceinline__ unsigned cvtpk(float lo, float hi) {
    unsigned r;
    asm("v_cvt_pk_bf16_f32 %0, %1, %2" : "=v"(r) : "v"(lo), "v"(hi));
    return r;
}
__device__ __forceinline__ float4v mfma16(short8v a, short8v b, float4v c) {
    return __builtin_amdgcn_mfma_f32_16x16x32_bf16(a, b, c, 0, 0, 0);
}
__device__ __forceinline__ void glds16(const void* g, void* l) {
    __builtin_amdgcn_global_load_lds(
        (const __attribute__((address_space(1))) void*)g,
        (__attribute__((address_space(3))) void*)l, 16, 0, 0);
}

// ---------------------------------------------------------------------------
// prep kernels
// ---------------------------------------------------------------------------
__global__ __launch_bounds__(256) void cast_k(const float* __restrict__ in,
                                              ushort* __restrict__ out) {
    size_t i = (size_t)blockIdx.x * blockDim.x + threadIdx.x;  // one float4
    float4 v = ld4(in + i * 4);
    ushort4 o = { f2bf(v.x), f2bf(v.y), f2bf(v.z), f2bf(v.w) };
    *(ushort4*)&out[i * 4] = o;
}

__global__ void copyf_k(const float* __restrict__ in, float* __restrict__ out,
                        float scale, int n) {
    int i = blockIdx.x * 256 + threadIdx.x;
    if (i < n) out[i] = in[i] * scale;
}

// fp32 [z][K][N] -> bf16 [z-mapped][N][K]   (weight transpose-cast, x scale)
__global__ __launch_bounds__(256) void wtrans_k(const float* __restrict__ in,
                                                ushort* __restrict__ out,
                                                int K, int N, int outBatchStride,
                                                float scale) {
    __shared__ float t[32][33];
    const int z = blockIdx.z;
    const float* ib = in + (size_t)z * K * N;
    ushort* ob = out + (size_t)z * outBatchStride;
    const int k0 = blockIdx.y * 32, n0 = blockIdx.x * 32;
    const int tx = threadIdx.x & 31, ty = threadIdx.x >> 5;   // ty 0..7
    #pragma unroll
    for (int i = 0; i < 4; ++i)
        t[ty + i * 8][tx] = ib[(size_t)(k0 + ty + i * 8) * N + n0 + tx];
    __syncthreads();
    #pragma unroll
    for (int i = 0; i < 4; ++i)
        ob[(size_t)(n0 + ty + i * 8) * K + k0 + tx] = f2bf(t[tx][ty + i * 8] * scale);
}

// bf16 [BH][S][64] -> [BH][64][S]   (V transpose for attention B-operand)
__global__ __launch_bounds__(256) void vtrans_k(const ushort* __restrict__ in,
                                                ushort* __restrict__ out) {
    __shared__ ushort t[32][36];
    const int bh = blockIdx.z;
    const int s0 = blockIdx.y * 32, d0 = blockIdx.x * 32;
    const int tx = threadIdx.x & 31, ty = threadIdx.x >> 5;
    #pragma unroll
    for (int i = 0; i < 4; ++i)
        t[ty + i * 8][tx] = in[((size_t)bh * S_ + s0 + ty + i * 8) * D_ + d0 + tx];
    __syncthreads();
    #pragma unroll
    for (int i = 0; i < 4; ++i)
        out[((size_t)bh * D_ + d0 + ty + i * 8) * S_ + s0 + tx] = t[tx][ty + i * 8];
}

// ---------------------------------------------------------------------------
// bf16 MFMA GEMM, 128x128 tile, BK=32, 256 thr (4 waves 2x2), m97 structure.
// A: bf16 [4096][K] row-major. Bt: bf16 [N][K] (k-contiguous). bias fp32 [N].
// OUTMODE: 0 = fp32 row-major, 1 = bf16 row-major, 2 = bf16 [mat][B][H][S][D]
// ---------------------------------------------------------------------------
template<int OUTMODE, int ACT>
__global__ __launch_bounds__(256) void gemm_bf16_k(
    const ushort* __restrict__ A, const ushort* __restrict__ Bt,
    const float* __restrict__ bias, void* __restrict__ C, int N, int K)
{
    __shared__ __align__(16) ushort At[128 * 32];
    __shared__ __align__(16) ushort Bts[128 * 32];
    const int tid = threadIdx.x, lane = tid & 63, w = tid >> 6;
    const int wm = w >> 1, wn = w & 1;
    const int q = lane & 15, g = lane >> 4;
    const int m0 = blockIdx.y * 128, n0 = blockIdx.x * 128;

    float4v acc[4][4];
    #pragma unroll
    for (int i = 0; i < 4; ++i)
        #pragma unroll
        for (int j = 0; j < 4; ++j) acc[i][j] = (float4v){0.f, 0.f, 0.f, 0.f};

    for (int k0 = 0; k0 < K; k0 += 32) {
        #pragma unroll
        for (int t = 0; t < 2; ++t) {
            const int cb = (w * 2 + t) * 64;
            const int c = cb + lane;
            const int row = c >> 2, kc = c & 3;
            glds16(&A [(size_t)(m0 + row) * K + k0 + kc * 8], &At [cb * 8]);
            glds16(&Bt[(size_t)(n0 + row) * K + k0 + kc * 8], &Bts[cb * 8]);
        }
        __syncthreads();
        short8v af[4], bf[4];
        #pragma unroll
        for (int i = 0; i < 4; ++i) {
            af[i] = *(const short8v*)&At [(wm * 64 + i * 16 + q) * 32 + g * 8];
            bf[i] = *(const short8v*)&Bts[(wn * 64 + i * 16 + q) * 32 + g * 8];
        }
        #pragma unroll
        for (int i = 0; i < 4; ++i)
            #pragma unroll
            for (int j = 0; j < 4; ++j)
                acc[i][j] = mfma16(af[i], bf[j], acc[i][j]);
        __syncthreads();
    }

    float bcol[4];
    #pragma unroll
    for (int j = 0; j < 4; ++j) bcol[j] = bias[n0 + wn * 64 + j * 16 + q];

    #pragma unroll
    for (int i = 0; i < 4; ++i) {
        #pragma unroll
        for (int j = 0; j < 4; ++j) {
            const int colg = n0 + wn * 64 + j * 16 + q;
            #pragma unroll
            for (int r = 0; r < 4; ++r) {
                const int rowg = m0 + wm * 64 + i * 16 + g * 4 + r;
                float v = acc[i][j][r] + bcol[j];
                if (ACT) v = fmaxf(v, 0.f);
                if (OUTMODE == 0) {
                    ((float*)C)[(size_t)rowg * N + colg] = v;
                } else if (OUTMODE == 1) {
                    ((ushort*)C)[(size_t)rowg * N + colg] = f2bf(v);
                } else {
                    const int mat = colg >> 10, h = (colg >> 6) & 15, d = colg & 63;
                    const int bb = rowg >> 11, s = rowg & 2047;
                    ((ushort*)C)[((((size_t)(mat * B_ + bb) * H_ + h) * S_) + s) * D_ + d] = f2bf(v);
                }
            }
        }
    }
}

// ---------------------------------------------------------------------------
// Flash attention, bf16 MFMA, swapped formulation. 8 waves x 16 q-rows (512 thr).
// KV tile = 128. Q pre-scaled by 0.125*log2e (folded into Wq) -> exp2 domain.
// Grid: flat 512 blocks; bh = id&31 (XCD locality), qb from id>>5 (causal:
// pairing map so co-resident pairs sum to 17 tiles).
// All LDS offsets: one base VGPR + compile-time immediates; kf/kvf selected
// via XOR (fields overlap q&7 swizzle bits -- additive would carry).
// LDS 64 KB -> 2 blocks/CU (16 waves). T13 exact defer-rescale.
// ---------------------------------------------------------------------------
template<int CAUSAL>
__global__ __launch_bounds__(512, 4) void fattn_k(
    const ushort* __restrict__ Qg, const ushort* __restrict__ Kg,
    const ushort* __restrict__ VTg, ushort* __restrict__ Og, int Skv)
{
    __shared__ __align__(16) ushort Kt[128 * 64];    // [kv][d] swizzled, 16 KB
    __shared__ __align__(16) ushort Vt[64 * 128];    // [d][kv] swizzled, 16 KB
    __shared__ __align__(16) ushort POt[128 * 128];  // P^T in-loop; O at end. 32 KB
    const int tid = threadIdx.x, lane = tid & 63, w = tid >> 6;  // w 0..7
    const int g = lane >> 4, q = lane & 15;
    const int id = blockIdx.x;
    const int bh = id & 31;
    const int t_ = id >> 5;
    const int qb = CAUSAL ? ((t_ < 8) ? t_ : 23 - t_) : t_;
    const int q0b = qb * 128;
    const int q0w = q0b + w * 16;
    const int qr = w * 16 + q;

    // staging sources (advance per tile); dest chunks linear, source pre-swizzled
    const int c0 = w * 64 + lane, c1 = 512 + c0;
    const ushort* kS0 = Kg + ((size_t)bh * Skv + (c0 >> 3)) * 64 + (size_t)(((c0 & 7) ^ ((c0 >> 3) & 7)) * 8);
    const ushort* kS1 = Kg + ((size_t)bh * Skv + (c1 >> 3)) * 64 + (size_t)(((c1 & 7) ^ ((c1 >> 3) & 7)) * 8);
    const ushort* vS0 = VTg + ((size_t)bh * 64 + (c0 >> 4)) * (size_t)Skv + (size_t)(((c0 & 15) ^ ((c0 >> 4) & 7)) * 8);
    const ushort* vS1 = VTg + ((size_t)bh * 64 + (c1 >> 4)) * (size_t)Skv + (size_t)(((c1 & 15) ^ ((c1 >> 4) & 7)) * 8);
    ushort* kD0 = &Kt[(size_t)(w * 64) * 8];
    ushort* kD1 = &Kt[(size_t)(512 + w * 64) * 8];
    ushort* vD0 = &Vt[(size_t)(w * 64) * 8];
    ushort* vD1 = &Vt[(size_t)(512 + w * 64) * 8];

    // Q fragments (Q pre-scaled in projection)
    short8v qf[2];
    #pragma unroll
    for (int kf = 0; kf < 2; ++kf)
        qf[kf] = *(const short8v*)&Qg[((size_t)bh * S_ + q0w + q) * 64 + kf * 32 + g * 8];

    // loop-invariant LDS byte bases
    const int swz = (g ^ (q & 7)) << 4;
    const int ktBase = q * 128 + swz;                     // + kvf*2048, ^ (kf<<6)
    const int vtBase = q * 256 + swz;                     // + df*4096, ^ (kf<<6)
    const int pfBase = qr * 256 + swz;                    // ^ (kf<<6)
    const int poBase = qr * 256 + ((((g >> 1) ^ (q & 7)) << 4) | ((g & 1) << 3)); // ^ (kvf<<5)

    float4v oacc[4];
    #pragma unroll
    for (int d2 = 0; d2 < 4; ++d2) oacc[d2] = (float4v){0.f, 0.f, 0.f, 0.f};
    float m_ = -1e30f, l_ = 0.f;

    const int ktiles = CAUSAL ? (qb + 1) : (Skv >> 7);

    for (int kt = 0; kt < ktiles; ++kt) {
        glds16(kS0, kD0); glds16(kS1, kD1);
        glds16(vS0, vD0); glds16(vS1, vD1);
        kS0 += 128 * 64; kS1 += 128 * 64; vS0 += 128; vS1 += 128;
        __syncthreads();   // includes vmcnt(0) drain of the glds16 queue

        // S^T = K . Q^T  (rows kv, cols q); st[kvf][r] = S^T[kvf*16+g*4+r][q]
        float4v st[8];
        #pragma unroll
        for (int kvf = 0; kvf < 8; ++kvf) {
            short8v k0 = *(const short8v*)((const char*)Kt + (ktBase + kvf * 2048));
            short8v k1 = *(const short8v*)((const char*)Kt + ((ktBase + kvf * 2048) ^ 64));
            st[kvf] = mfma16(k0, qf[0], (float4v){0.f, 0.f, 0.f, 0.f});
            st[kvf] = mfma16(k1, qf[1], st[kvf]);
        }

        if (CAUSAL && kt == ktiles - 1) {       // diagonal tile only (kv0 == q0b)
            const int qg_ = q0w + q;
            #pragma unroll
            for (int kvf = 0; kvf < 8; ++kvf)
                #pragma unroll
                for (int r = 0; r < 4; ++r)
                    if (q0b + kvf * 16 + g * 4 + r > qg_) st[kvf][r] = -1e9f;
        }

        // row max (tree + 2 shuffles)
        float mA[8];
        #pragma unroll
        for (int kvf = 0; kvf < 8; ++kvf)
            mA[kvf] = fmaxf(fmaxf(st[kvf][0], st[kvf][1]), fmaxf(st[kvf][2], st[kvf][3]));
        float mx = fmaxf(fmaxf(fmaxf(mA[0], mA[1]), fmaxf(mA[2], mA[3])),
                         fmaxf(fmaxf(mA[4], mA[5]), fmaxf(mA[6], mA[7])));
        mx = fmaxf(mx, __shfl_xor(mx, 16));
        mx = fmaxf(mx, __shfl_xor(mx, 32));

        if (!__all(mx <= m_)) {                 // T13: skip is exact (f == 1)
            const float nm = fmaxf(m_, mx);
            const float f = exp2f(m_ - nm);
            l_ *= f;
            #pragma unroll
            for (int d2 = 0; d2 < 4; ++d2) oacc[d2] = oacc[d2] * f;
            m_ = nm;
        }

        // exp + per-lane partial sum (row-reduce deferred to epilogue)
        float sA[8];
        #pragma unroll
        for (int kvf = 0; kvf < 8; ++kvf) {
            #pragma unroll
            for (int r = 0; r < 4; ++r) st[kvf][r] = exp2f(st[kvf][r] - m_);
            sA[kvf] = (st[kvf][0] + st[kvf][1]) + (st[kvf][2] + st[kvf][3]);
        }
        l_ += ((sA[0] + sA[1]) + (sA[2] + sA[3])) + ((sA[4] + sA[5]) + (sA[6] + sA[7]));

        // pack P^T rows into POt (bf16), own rows only
        #pragma unroll
        for (int kvf = 0; kvf < 8; ++kvf) {
            uint2 pv;
            pv.x = cvtpk(st[kvf][0], st[kvf][1]);
            pv.y = cvtpk(st[kvf][2], st[kvf][3]);
            *(uint2*)((char*)POt + (poBase ^ (kvf << 5))) = pv;
        }

        // O^T += V^T . P^T
        short8v pf[4];
        #pragma unroll
        for (int kf = 0; kf < 4; ++kf)
            pf[kf] = *(const short8v*)((const char*)POt + (pfBase ^ (kf << 6)));
        #pragma unroll
        for (int df = 0; df < 4; ++df) {
            const int vb = vtBase + df * 4096;
            #pragma unroll
            for (int kf = 0; kf < 4; ++kf) {
                short8v vfr = *(const short8v*)((const char*)Vt + (vb ^ (kf << 6)));
                oacc[df] = mfma16(vfr, pf[kf], oacc[df]);
            }
        }
        __syncthreads();   // protect Kt/Vt (and cross-wave POt) before next stage
    }

    // row sum across the 4 g-lanes, then normalize
    float lr = l_;
    lr += __shfl_xor(lr, 16);
    lr += __shfl_xor(lr, 32);
    const float inv = 1.f / lr;

    __syncthreads();       // Ot rows (stride 128B) overlay other waves' Pt space
    #pragma unroll
    for (int df = 0; df < 4; ++df) {
        uint2 ov;
        ov.x = cvtpk(oacc[df][0] * inv, oacc[df][1] * inv);
        ov.y = cvtpk(oacc[df][2] * inv, oacc[df][3] * inv);
        *(uint2*)((char*)POt + qr * 128 +
                  ((((2 * df + (g >> 1)) ^ (q & 7)) << 4) | ((g & 1) << 3))) = ov;
    }
    __syncthreads();
    const int b = bh >> 4, h = bh & 15;
    #pragma unroll
    for (int t = 0; t < 2; ++t) {
        const int c = t * 512 + tid;
        const int qrow = c >> 3, ch = c & 7;
        short8v v = *(const short8v*)((char*)POt + qrow * 128 + ((ch ^ (qrow & 7)) << 4));
        *(short8v*)&Og[((size_t)(b * S_ + q0b + qrow)) * M_ + h * 64 + ch * 8] = v;
    }
}

// ---------------------------------------------------------------------------
// Fused residual-add + LayerNorm. X bf16, residual fp32; emits fp32 (+bf16).
// ---------------------------------------------------------------------------
template<int EMITB>
__global__ __launch_bounds__(256) void ln_k(
    const ushort* __restrict__ X, const float* __restrict__ Rz,
    const float* __restrict__ g, const float* __restrict__ be,
    float* __restrict__ outf, ushort* __restrict__ outb)
{
    __shared__ float red[8];
    const int row = blockIdx.x, tid = threadIdx.x;
    const int lane = tid & 63, w = tid >> 6;

    ushort4 xu = *(const ushort4*)&X[(size_t)row * M_ + tid * 4];
    float4 rr = ld4(Rz + (size_t)row * M_ + tid * 4);
    float4 x = make_float4(bf2f(xu.x) + rr.x, bf2f(xu.y) + rr.y,
                           bf2f(xu.z) + rr.z, bf2f(xu.w) + rr.w);

    float sm = x.x + x.y + x.z + x.w;
    #pragma unroll
    for (int off = 1; off < 64; off <<= 1) sm += __shfl_xor(sm, off);
    if (lane == 0) red[w] = sm;
    __syncthreads();
    const float mean = (red[0] + red[1] + red[2] + red[3]) * (1.f / M_);

    x.x -= mean; x.y -= mean; x.z -= mean; x.w -= mean;
    float vs = x.x * x.x + x.y * x.y + x.z * x.z + x.w * x.w;
    #pragma unroll
    for (int off = 1; off < 64; off <<= 1) vs += __shfl_xor(vs, off);
    if (lane == 0) red[4 + w] = vs;
    __syncthreads();
    const float var = (red[4] + red[5] + red[6] + red[7]) * (1.f / M_);
    const float rs = rsqrtf(var + 1e-5f);

    float4 gg = ld4(g + tid * 4), bb = ld4(be + tid * 4);
    float4 y = make_float4(x.x * rs * gg.x + bb.x, x.y * rs * gg.y + bb.y,
                           x.z * rs * gg.z + bb.z, x.w * rs * gg.w + bb.w);
    *(float4*)(outf + (size_t)row * M_ + tid * 4) = y;
    if (EMITB) {
        ushort4 ob = { f2bf(y.x), f2bf(y.y), f2bf(y.z), f2bf(y.w) };
        *(ushort4*)&outb[(size_t)row * M_ + tid * 4] = ob;
    }
}

// ---------------------------------------------------------------------------
extern "C" void kernel_launch(void* const* d_in, const int* in_sizes, int n_in,
                              void* d_out, int out_size, void* d_ws, size_t ws_size,
                              hipStream_t stream)
{
    const float* input = (const float*)d_in[0];
    const float* enc   = (const float*)d_in[1];
    const float* Wq1 = (const float*)d_in[2];  const float* bq1 = (const float*)d_in[3];
    const float* Wk1 = (const float*)d_in[4];  const float* bk1 = (const float*)d_in[5];
    const float* Wv1 = (const float*)d_in[6];  const float* bv1 = (const float*)d_in[7];
    const float* Wo1 = (const float*)d_in[8];  const float* bo1 = (const float*)d_in[9];
    const float* ln1g = (const float*)d_in[10]; const float* ln1b = (const float*)d_in[11];
    const float* Wq2 = (const float*)d_in[12]; const float* bq2 = (const float*)d_in[13];
    const float* Wk2 = (const float*)d_in[14]; const float* bk2 = (const float*)d_in[15];
    const float* Wv2 = (const float*)d_in[16]; const float* bv2 = (const float*)d_in[17];
    const float* Wo2 = (const float*)d_in[18]; const float* bo2 = (const float*)d_in[19];
    const float* ln2g = (const float*)d_in[20]; const float* ln2b = (const float*)d_in[21];
    const float* Wf1 = (const float*)d_in[22]; const float* bf1 = (const float*)d_in[23];
    const float* Wf2 = (const float*)d_in[24]; const float* bf2 = (const float*)d_in[25];
    const float* ln3g = (const float*)d_in[26]; const float* ln3b = (const float*)d_in[27];

    const float SC = 0.18033688011112042f;     // 0.125 * log2(e)

    char* W = (char*)d_ws;
    #define OFS(mb) ((void*)(W + (size_t)(mb) * 1024 * 1024))
    ushort* x0b    = (ushort*)OFS(0);
    ushort* encb   = (ushort*)OFS(8);
    ushort* WqkvT1 = (ushort*)OFS(16);
    ushort* Wo1T   = (ushort*)OFS(22);
    ushort* Wq2T   = (ushort*)OFS(24);
    ushort* WkvT2  = (ushort*)OFS(26);
    ushort* Wo2T   = (ushort*)OFS(30);
    ushort* Wf1T   = (ushort*)OFS(32);
    ushort* Wf2T   = (ushort*)OFS(36);
    float*  biasQKV1 = (float*)OFS(40);
    float*  biasKV2  = (float*)((char*)OFS(40) + 16384);
    float*  biasQ2   = (float*)((char*)OFS(40) + 32768);
    ushort* QKV1   = (ushort*)OFS(41);   // [3][B][H][S][D]
    ushort* VT1    = (ushort*)OFS(65);
    ushort* att1b  = (ushort*)OFS(73);
    ushort* o1b    = (ushort*)OFS(81);
    float*  out1f  = (float*)OFS(41);
    ushort* out1b  = (ushort*)OFS(57);
    ushort* Q2     = (ushort*)OFS(65);
    ushort* KV2    = (ushort*)OFS(73);   // [2][B][H][S][D]
    ushort* VT2    = (ushort*)OFS(0);
    ushort* att2b  = (ushort*)OFS(8);
    ushort* o2b    = (ushort*)OFS(65);
    float*  out2f  = (float*)OFS(73);
    ushort* out2b  = (ushort*)OFS(0);
    ushort* ff1b   = (ushort*)OFS(41);
    ushort* ff2b   = (ushort*)OFS(57);
    float*  out    = (float*)d_out;
    const size_t MAT = (size_t)B_ * H_ * S_ * D_;   // 4 Mi elements

    dim3 blk(256);
    dim3 blkA(512);

    // ---- prep: casts, weight transposes (Wq scaled by SC), bias packs ----
    cast_k<<<4096, blk, 0, stream>>>(input, x0b);
    cast_k<<<4096, blk, 0, stream>>>(enc, encb);
    wtrans_k<<<dim3(2, 32, 16), blk, 0, stream>>>(Wq1, WqkvT1,               1024, 64, 64 * 1024, SC);
    wtrans_k<<<dim3(2, 32, 16), blk, 0, stream>>>(Wk1, WqkvT1 + 1024 * 1024, 1024, 64, 64 * 1024, 1.f);
    wtrans_k<<<dim3(2, 32, 16), blk, 0, stream>>>(Wv1, WqkvT1 + 2048 * 1024, 1024, 64, 64 * 1024, 1.f);
    wtrans_k<<<dim3(32, 32, 1), blk, 0, stream>>>(Wo1, Wo1T, 1024, 1024, 0, 1.f);
    wtrans_k<<<dim3(2, 32, 16), blk, 0, stream>>>(Wq2, Wq2T, 1024, 64, 64 * 1024, SC);
    wtrans_k<<<dim3(2, 32, 16), blk, 0, stream>>>(Wk2, WkvT2,               1024, 64, 64 * 1024, 1.f);
    wtrans_k<<<dim3(2, 32, 16), blk, 0, stream>>>(Wv2, WkvT2 + 1024 * 1024, 1024, 64, 64 * 1024, 1.f);
    wtrans_k<<<dim3(32, 32, 1), blk, 0, stream>>>(Wo2, Wo2T, 1024, 1024, 0, 1.f);
    wtrans_k<<<dim3(64, 32, 1), blk, 0, stream>>>(Wf1, Wf1T, 1024, 2048, 0, 1.f);
    wtrans_k<<<dim3(32, 64, 1), blk, 0, stream>>>(Wf2, Wf2T, 2048, 1024, 0, 1.f);
    copyf_k<<<4, blk, 0, stream>>>(bq1, biasQKV1,        SC,  1024);
    copyf_k<<<4, blk, 0, stream>>>(bk1, biasQKV1 + 1024, 1.f, 1024);
    copyf_k<<<4, blk, 0, stream>>>(bv1, biasQKV1 + 2048, 1.f, 1024);
    copyf_k<<<4, blk, 0, stream>>>(bk2, biasKV2,         1.f, 1024);
    copyf_k<<<4, blk, 0, stream>>>(bv2, biasKV2 + 1024,  1.f, 1024);
    copyf_k<<<4, blk, 0, stream>>>(bq2, biasQ2,          SC,  1024);

    // ---- masked self-attention ----
    gemm_bf16_k<2, 0><<<dim3(24, 32), blk, 0, stream>>>(x0b, WqkvT1, biasQKV1, QKV1, 3072, 1024);
    vtrans_k<<<dim3(2, 64, 32), blk, 0, stream>>>(QKV1 + 2 * MAT, VT1);
    fattn_k<1><<<dim3(512), blkA, 0, stream>>>(QKV1, QKV1 + MAT, VT1, att1b, S_);
    gemm_bf16_k<1, 0><<<dim3(8, 32), blk, 0, stream>>>(att1b, Wo1T, bo1, o1b, 1024, 1024);
    ln_k<1><<<dim3(R_), blk, 0, stream>>>(o1b, input, ln1g, ln1b, out1f, out1b);

    // ---- cross-attention ----
    gemm_bf16_k<2, 0><<<dim3(8, 32), blk, 0, stream>>>(out1b, Wq2T, biasQ2, Q2, 1024, 1024);
    gemm_bf16_k<2, 0><<<dim3(16, 32), blk, 0, stream>>>(encb, WkvT2, biasKV2, KV2, 2048, 1024);
    vtrans_k<<<dim3(2, 64, 32), blk, 0, stream>>>(KV2 + MAT, VT2);
    fattn_k<0><<<dim3(512), blkA, 0, stream>>>(Q2, KV2, VT2, att2b, S_);
    gemm_bf16_k<1, 0><<<dim3(8, 32), blk, 0, stream>>>(att2b, Wo2T, bo2, o2b, 1024, 1024);
    ln_k<1><<<dim3(R_), blk, 0, stream>>>(o2b, out1f, ln2g, ln2b, out2f, out2b);

    // ---- FFN ----
    gemm_bf16_k<1, 1><<<dim3(16, 32), blk, 0, stream>>>(out2b, Wf1T, bf1, ff1b, 2048, 1024);
    gemm_bf16_k<1, 0><<<dim3(8, 32), blk, 0, stream>>>(ff1b, Wf2T, bf2, ff2b, 1024, 2048);
    ln_k<0><<<dim3(R_), blk, 0, stream>>>(ff2b, out2f, ln3g, ln3b, out, nullptr);
    #undef OFS
}

// Round 6
// 418.056 us; speedup vs baseline: 6.8516x; 1.0068x over previous
//
#include <hip/hip_runtime.h>
#include <math.h>

#define B_ 2
#define S_ 2048
#define M_ 1024
#define H_ 16
#define D_ 64
#define R_ (B_*S_)          // 4096 rows

typedef __attribute__((ext_vector_type(8))) short short8v;   // 8 bf16 = 4 VGPR
typedef __attribute__((ext_vector_type(4))) float float4v;

__device__ __forceinline__ float4 ld4(const float* p) {
    return *(const float4* __restrict__)p;
}

__device__ __forceinline__ ushort f2bf(float f) {            // RNE
    union { float f; unsigned u; } x; x.f = f;
    unsigned u = x.u + 0x7fffu + ((x.u >> 16) & 1u);
    return (ushort)(u >> 16);
}
__device__ __forceinline__ float bf2f(ushort s) {
    union { unsigned u; float f; } x; x.u = ((unsigned)s) << 16; return x.f;
}
__device__ __forceinline__ unsigned cvtpk(float lo, float hi) {
    unsigned r;
    asm("v_cvt_pk_bf16_f32 %0, %1, %2" : "=v"(r) : "v"(lo), "v"(hi));
    return r;
}
__device__ __forceinline__ float4v mfma16(short8v a, short8v b, float4v c) {
    return __builtin_amdgcn_mfma_f32_16x16x32_bf16(a, b, c, 0, 0, 0);
}
__device__ __forceinline__ void glds16(const void* g, void* l) {
    __builtin_amdgcn_global_load_lds(
        (const __attribute__((address_space(1))) void*)g,
        (__attribute__((address_space(3))) void*)l, 16, 0, 0);
}

// ---------------------------------------------------------------------------
// prep kernels
// ---------------------------------------------------------------------------
__global__ __launch_bounds__(256) void cast_k(const float* __restrict__ in,
                                              ushort* __restrict__ out) {
    size_t i = (size_t)blockIdx.x * blockDim.x + threadIdx.x;  // one float4
    float4 v = ld4(in + i * 4);
    ushort4 o = { f2bf(v.x), f2bf(v.y), f2bf(v.z), f2bf(v.w) };
    *(ushort4*)&out[i * 4] = o;
}

__global__ void copyf_k(const float* __restrict__ in, float* __restrict__ out,
                        float scale, int n) {
    int i = blockIdx.x * 256 + threadIdx.x;
    if (i < n) out[i] = in[i] * scale;
}

// fp32 [z][K][N] -> bf16 [z-mapped][N][K]   (weight transpose-cast, x scale)
__global__ __launch_bounds__(256) void wtrans_k(const float* __restrict__ in,
                                                ushort* __restrict__ out,
                                                int K, int N, int outBatchStride,
                                                float scale) {
    __shared__ float t[32][33];
    const int z = blockIdx.z;
    const float* ib = in + (size_t)z * K * N;
    ushort* ob = out + (size_t)z * outBatchStride;
    const int k0 = blockIdx.y * 32, n0 = blockIdx.x * 32;
    const int tx = threadIdx.x & 31, ty = threadIdx.x >> 5;   // ty 0..7
    #pragma unroll
    for (int i = 0; i < 4; ++i)
        t[ty + i * 8][tx] = ib[(size_t)(k0 + ty + i * 8) * N + n0 + tx];
    __syncthreads();
    #pragma unroll
    for (int i = 0; i < 4; ++i)
        ob[(size_t)(n0 + ty + i * 8) * K + k0 + tx] = f2bf(t[tx][ty + i * 8] * scale);
}

// bf16 [BH][S][64] -> [BH][64][S]   (V transpose for attention B-operand)
__global__ __launch_bounds__(256) void vtrans_k(const ushort* __restrict__ in,
                                                ushort* __restrict__ out) {
    __shared__ ushort t[32][36];
    const int bh = blockIdx.z;
    const int s0 = blockIdx.y * 32, d0 = blockIdx.x * 32;
    const int tx = threadIdx.x & 31, ty = threadIdx.x >> 5;
    #pragma unroll
    for (int i = 0; i < 4; ++i)
        t[ty + i * 8][tx] = in[((size_t)bh * S_ + s0 + ty + i * 8) * D_ + d0 + tx];
    __syncthreads();
    #pragma unroll
    for (int i = 0; i < 4; ++i)
        out[((size_t)bh * D_ + d0 + ty + i * 8) * S_ + s0 + tx] = t[tx][ty + i * 8];
}

// ---------------------------------------------------------------------------
// bf16 MFMA GEMM, 128x128 tile, BK=32, 256 thr (4 waves 2x2), m97 structure.
// A: bf16 [4096][K] row-major. Bt: bf16 [N][K] (k-contiguous). bias fp32 [N].
// OUTMODE: 0 = fp32 row-major, 1 = bf16 row-major, 2 = bf16 [mat][B][H][S][D]
// ---------------------------------------------------------------------------
template<int OUTMODE, int ACT>
__global__ __launch_bounds__(256) void gemm_bf16_k(
    const ushort* __restrict__ A, const ushort* __restrict__ Bt,
    const float* __restrict__ bias, void* __restrict__ C, int N, int K)
{
    __shared__ __align__(16) ushort At[128 * 32];
    __shared__ __align__(16) ushort Bts[128 * 32];
    const int tid = threadIdx.x, lane = tid & 63, w = tid >> 6;
    const int wm = w >> 1, wn = w & 1;
    const int q = lane & 15, g = lane >> 4;
    const int m0 = blockIdx.y * 128, n0 = blockIdx.x * 128;

    float4v acc[4][4];
    #pragma unroll
    for (int i = 0; i < 4; ++i)
        #pragma unroll
        for (int j = 0; j < 4; ++j) acc[i][j] = (float4v){0.f, 0.f, 0.f, 0.f};

    for (int k0 = 0; k0 < K; k0 += 32) {
        #pragma unroll
        for (int t = 0; t < 2; ++t) {
            const int cb = (w * 2 + t) * 64;
            const int c = cb + lane;
            const int row = c >> 2, kc = c & 3;
            glds16(&A [(size_t)(m0 + row) * K + k0 + kc * 8], &At [cb * 8]);
            glds16(&Bt[(size_t)(n0 + row) * K + k0 + kc * 8], &Bts[cb * 8]);
        }
        __syncthreads();
        short8v af[4], bf[4];
        #pragma unroll
        for (int i = 0; i < 4; ++i) {
            af[i] = *(const short8v*)&At [(wm * 64 + i * 16 + q) * 32 + g * 8];
            bf[i] = *(const short8v*)&Bts[(wn * 64 + i * 16 + q) * 32 + g * 8];
        }
        #pragma unroll
        for (int i = 0; i < 4; ++i)
            #pragma unroll
            for (int j = 0; j < 4; ++j)
                acc[i][j] = mfma16(af[i], bf[j], acc[i][j]);
        __syncthreads();
    }

    float bcol[4];
    #pragma unroll
    for (int j = 0; j < 4; ++j) bcol[j] = bias[n0 + wn * 64 + j * 16 + q];

    #pragma unroll
    for (int i = 0; i < 4; ++i) {
        #pragma unroll
        for (int j = 0; j < 4; ++j) {
            const int colg = n0 + wn * 64 + j * 16 + q;
            #pragma unroll
            for (int r = 0; r < 4; ++r) {
                const int rowg = m0 + wm * 64 + i * 16 + g * 4 + r;
                float v = acc[i][j][r] + bcol[j];
                if (ACT) v = fmaxf(v, 0.f);
                if (OUTMODE == 0) {
                    ((float*)C)[(size_t)rowg * N + colg] = v;
                } else if (OUTMODE == 1) {
                    ((ushort*)C)[(size_t)rowg * N + colg] = f2bf(v);
                } else {
                    const int mat = colg >> 10, h = (colg >> 6) & 15, d = colg & 63;
                    const int bb = rowg >> 11, s = rowg & 2047;
                    ((ushort*)C)[((((size_t)(mat * B_ + bb) * H_ + h) * S_) + s) * D_ + d] = f2bf(v);
                }
            }
        }
    }
}

// ---------------------------------------------------------------------------
// Flash attention, bf16 MFMA, swapped formulation.
// 256 thr = 4 waves x 16 q-rows (q-tile 64). KV tile 64, DOUBLE-BUFFERED:
// stage(t+1) issued before compute(t); ONE barrier per tile drains it.
// LDS 40 KB -> 4 independent blocks/CU (inter-block overlap hides idle).
// Grid 1024 = 32 q-tiles x 32 bh; bh = id&31 (XCD L2 locality); causal
// dispatches longest q-tiles first (greedy balance, max chain 32 tiles).
// Q pre-scaled by 0.125*log2e (folded into Wq/bq) -> exp2 domain.
// T13 exact defer-rescale; T5 setprio around MFMA clusters.
// ---------------------------------------------------------------------------
template<int CAUSAL>
__global__ __launch_bounds__(256, 4) void fattn_k(
    const ushort* __restrict__ Qg, const ushort* __restrict__ Kg,
    const ushort* __restrict__ VTg, ushort* __restrict__ Og, int Skv)
{
    __shared__ __align__(16) ushort Kt[2][64 * 64];   // [kv][d] swizzled, 8 KB x2
    __shared__ __align__(16) ushort Vt[2][64 * 64];   // [d][kv] swizzled, 8 KB x2
    __shared__ __align__(16) ushort Pt[64 * 64];      // P^T in-loop; O at end. 8 KB
    const int tid = threadIdx.x, lane = tid & 63, w = tid >> 6;   // w 0..3
    const int g = lane >> 4, q = lane & 15;
    const int id = blockIdx.x;
    const int bh = id & 31;
    const int qb = CAUSAL ? (31 - (id >> 5)) : (id >> 5);
    const int q0b = qb * 64;
    const int q0w = q0b + w * 16;
    const int qr = w * 16 + q;

    // staging sources (2 chunks per thread per matrix), pre-swizzled
    const int c0 = tid, c1 = tid + 256;
    const ushort* kS0 = Kg + ((size_t)bh * Skv + (c0 >> 3)) * 64 + (((c0 & 7) ^ ((c0 >> 3) & 7)) * 8);
    const ushort* kS1 = Kg + ((size_t)bh * Skv + (c1 >> 3)) * 64 + (((c1 & 7) ^ ((c1 >> 3) & 7)) * 8);
    const ushort* vS0 = VTg + ((size_t)bh * 64 + (c0 >> 3)) * (size_t)Skv + (((c0 & 7) ^ ((c0 >> 3) & 7)) * 8);
    const ushort* vS1 = VTg + ((size_t)bh * 64 + (c1 >> 3)) * (size_t)Skv + (((c1 & 7) ^ ((c1 >> 3) & 7)) * 8);

#define STAGE(nb) do { \
        glds16(kS0, &Kt[nb][(w * 64) * 8]); \
        glds16(kS1, &Kt[nb][(256 + w * 64) * 8]); \
        glds16(vS0, &Vt[nb][(w * 64) * 8]); \
        glds16(vS1, &Vt[nb][(256 + w * 64) * 8]); \
        kS0 += 64 * 64; kS1 += 64 * 64; vS0 += 64; vS1 += 64; } while (0)

    // Q fragments (Q pre-scaled in projection)
    short8v qf[2];
    #pragma unroll
    for (int kf = 0; kf < 2; ++kf)
        qf[kf] = *(const short8v*)&Qg[((size_t)bh * S_ + q0w + q) * 64 + kf * 32 + g * 8];

    // loop-invariant LDS byte bases (row % 8 == q % 7 ... == q&7 everywhere)
    const int swz = (g ^ (q & 7)) << 4;
    const int ktB = q * 128 + swz;                    // + kvf*2048 ; ^ (kf<<6)
    const int vtB = q * 128 + swz;                    // + df*2048  ; ^ (kf<<6)
    const int pfB = qr * 128 + swz;                   // ^ (kf<<6)
    const int poB = qr * 128 + ((((g >> 1) ^ (q & 7)) << 4) | ((g & 1) << 3)); // ^ (kvf<<5)

    float4v oacc[4];
    #pragma unroll
    for (int d2 = 0; d2 < 4; ++d2) oacc[d2] = (float4v){0.f, 0.f, 0.f, 0.f};
    float m_ = -1e30f, l_ = 0.f;

    const int ktiles = CAUSAL ? (qb + 1) : (Skv >> 6);
    int cur = 0;

    STAGE(0);
    __syncthreads();

    for (int kt = 0; kt < ktiles; ++kt) {
        if (kt + 1 < ktiles) STAGE(cur ^ 1);          // issue-early: flies under compute
        const char* ktp = (const char*)Kt + cur * 8192;
        const char* vtp = (const char*)Vt + cur * 8192;

        // S^T = K . Q^T  (rows kv, cols q); st[kvf][r] = S^T[kvf*16+g*4+r][q]
        float4v st[4];
        __builtin_amdgcn_s_setprio(1);
        #pragma unroll
        for (int kvf = 0; kvf < 4; ++kvf) {
            short8v k0 = *(const short8v*)(ktp + (ktB + kvf * 2048));
            short8v k1 = *(const short8v*)(ktp + ((ktB + kvf * 2048) ^ 64));
            st[kvf] = mfma16(k0, qf[0], (float4v){0.f, 0.f, 0.f, 0.f});
            st[kvf] = mfma16(k1, qf[1], st[kvf]);
        }
        __builtin_amdgcn_s_setprio(0);

        if (CAUSAL && kt == ktiles - 1) {             // diagonal tile (kv0 == q0b)
            const int qg_ = q0w + q;
            #pragma unroll
            for (int kvf = 0; kvf < 4; ++kvf)
                #pragma unroll
                for (int r = 0; r < 4; ++r)
                    if (q0b + kvf * 16 + g * 4 + r > qg_) st[kvf][r] = -1e9f;
        }

        // row max (tree + 2 shuffles)
        float mA[4];
        #pragma unroll
        for (int kvf = 0; kvf < 4; ++kvf)
            mA[kvf] = fmaxf(fmaxf(st[kvf][0], st[kvf][1]), fmaxf(st[kvf][2], st[kvf][3]));
        float mx = fmaxf(fmaxf(mA[0], mA[1]), fmaxf(mA[2], mA[3]));
        mx = fmaxf(mx, __shfl_xor(mx, 16));
        mx = fmaxf(mx, __shfl_xor(mx, 32));

        if (!__all(mx <= m_)) {                       // T13: skip is exact (f == 1)
            const float nm = fmaxf(m_, mx);
            const float f = exp2f(m_ - nm);
            l_ *= f;
            #pragma unroll
            for (int d2 = 0; d2 < 4; ++d2) oacc[d2] = oacc[d2] * f;
            m_ = nm;
        }

        // exp + per-lane partial sum (row-reduce deferred to epilogue)
        float sA[4];
        #pragma unroll
        for (int kvf = 0; kvf < 4; ++kvf) {
            #pragma unroll
            for (int r = 0; r < 4; ++r) st[kvf][r] = exp2f(st[kvf][r] - m_);
            sA[kvf] = (st[kvf][0] + st[kvf][1]) + (st[kvf][2] + st[kvf][3]);
        }
        l_ += (sA[0] + sA[1]) + (sA[2] + sA[3]);

        // pack P^T rows into Pt (own wave's rows only; same-wave write->read)
        #pragma unroll
        for (int kvf = 0; kvf < 4; ++kvf) {
            uint2 pv;
            pv.x = cvtpk(st[kvf][0], st[kvf][1]);
            pv.y = cvtpk(st[kvf][2], st[kvf][3]);
            *(uint2*)((char*)Pt + (poB ^ (kvf << 5))) = pv;
        }

        // O^T += V^T . P^T
        short8v pf[2];
        #pragma unroll
        for (int kf = 0; kf < 2; ++kf)
            pf[kf] = *(const short8v*)((const char*)Pt + (pfB ^ (kf << 6)));
        __builtin_amdgcn_s_setprio(1);
        #pragma unroll
        for (int df = 0; df < 4; ++df) {
            #pragma unroll
            for (int kf = 0; kf < 2; ++kf) {
                short8v vfr = *(const short8v*)(vtp + ((vtB + df * 2048) ^ (kf << 6)));
                oacc[df] = mfma16(vfr, pf[kf], oacc[df]);
            }
        }
        __builtin_amdgcn_s_setprio(0);

        __syncthreads();       // drains stage(t+1) vmcnt + protects Kt/Vt[cur]
        cur ^= 1;
    }
#undef STAGE

    // row sum across the 4 g-lanes, then normalize
    float lr = l_;
    lr += __shfl_xor(lr, 16);
    lr += __shfl_xor(lr, 32);
    const float inv = 1.f / lr;

    // stage O into Pt (own wave's rows -- no barrier needed before writes)
    #pragma unroll
    for (int df = 0; df < 4; ++df) {
        uint2 ov;
        ov.x = cvtpk(oacc[df][0] * inv, oacc[df][1] * inv);
        ov.y = cvtpk(oacc[df][2] * inv, oacc[df][3] * inv);
        *(uint2*)((char*)Pt + qr * 128 +
                  ((((2 * df + (g >> 1)) ^ (q & 7)) << 4) | ((g & 1) << 3))) = ov;
    }
    __syncthreads();
    const int b = bh >> 4, h = bh & 15;
    #pragma unroll
    for (int t = 0; t < 2; ++t) {
        const int c = t * 256 + tid;
        const int qrow = c >> 3, ch = c & 7;
        short8v v = *(const short8v*)((char*)Pt + qrow * 128 + ((ch ^ (qrow & 7)) << 4));
        *(short8v*)&Og[((size_t)(b * S_ + q0b + qrow)) * M_ + h * 64 + ch * 8] = v;
    }
}

// ---------------------------------------------------------------------------
// Fused residual-add + LayerNorm. X bf16, residual fp32; emits fp32 (+bf16).
// ---------------------------------------------------------------------------
template<int EMITB>
__global__ __launch_bounds__(256) void ln_k(
    const ushort* __restrict__ X, const float* __restrict__ Rz,
    const float* __restrict__ g, const float* __restrict__ be,
    float* __restrict__ outf, ushort* __restrict__ outb)
{
    __shared__ float red[8];
    const int row = blockIdx.x, tid = threadIdx.x;
    const int lane = tid & 63, w = tid >> 6;

    ushort4 xu = *(const ushort4*)&X[(size_t)row * M_ + tid * 4];
    float4 rr = ld4(Rz + (size_t)row * M_ + tid * 4);
    float4 x = make_float4(bf2f(xu.x) + rr.x, bf2f(xu.y) + rr.y,
                           bf2f(xu.z) + rr.z, bf2f(xu.w) + rr.w);

    float sm = x.x + x.y + x.z + x.w;
    #pragma unroll
    for (int off = 1; off < 64; off <<= 1) sm += __shfl_xor(sm, off);
    if (lane == 0) red[w] = sm;
    __syncthreads();
    const float mean = (red[0] + red[1] + red[2] + red[3]) * (1.f / M_);

    x.x -= mean; x.y -= mean; x.z -= mean; x.w -= mean;
    float vs = x.x * x.x + x.y * x.y + x.z * x.z + x.w * x.w;
    #pragma unroll
    for (int off = 1; off < 64; off <<= 1) vs += __shfl_xor(vs, off);
    if (lane == 0) red[4 + w] = vs;
    __syncthreads();
    const float var = (red[4] + red[5] + red[6] + red[7]) * (1.f / M_);
    const float rs = rsqrtf(var + 1e-5f);

    float4 gg = ld4(g + tid * 4), bb = ld4(be + tid * 4);
    float4 y = make_float4(x.x * rs * gg.x + bb.x, x.y * rs * gg.y + bb.y,
                           x.z * rs * gg.z + bb.z, x.w * rs * gg.w + bb.w);
    *(float4*)(outf + (size_t)row * M_ + tid * 4) = y;
    if (EMITB) {
        ushort4 ob = { f2bf(y.x), f2bf(y.y), f2bf(y.z), f2bf(y.w) };
        *(ushort4*)&outb[(size_t)row * M_ + tid * 4] = ob;
    }
}

// ---------------------------------------------------------------------------
extern "C" void kernel_launch(void* const* d_in, const int* in_sizes, int n_in,
                              void* d_out, int out_size, void* d_ws, size_t ws_size,
                              hipStream_t stream)
{
    const float* input = (const float*)d_in[0];
    const float* enc   = (const float*)d_in[1];
    const float* Wq1 = (const float*)d_in[2];  const float* bq1 = (const float*)d_in[3];
    const float* Wk1 = (const float*)d_in[4];  const float* bk1 = (const float*)d_in[5];
    const float* Wv1 = (const float*)d_in[6];  const float* bv1 = (const float*)d_in[7];
    const float* Wo1 = (const float*)d_in[8];  const float* bo1 = (const float*)d_in[9];
    const float* ln1g = (const float*)d_in[10]; const float* ln1b = (const float*)d_in[11];
    const float* Wq2 = (const float*)d_in[12]; const float* bq2 = (const float*)d_in[13];
    const float* Wk2 = (const float*)d_in[14]; const float* bk2 = (const float*)d_in[15];
    const float* Wv2 = (const float*)d_in[16]; const float* bv2 = (const float*)d_in[17];
    const float* Wo2 = (const float*)d_in[18]; const float* bo2 = (const float*)d_in[19];
    const float* ln2g = (const float*)d_in[20]; const float* ln2b = (const float*)d_in[21];
    const float* Wf1 = (const float*)d_in[22]; const float* bf1 = (const float*)d_in[23];
    const float* Wf2 = (const float*)d_in[24]; const float* bf2 = (const float*)d_in[25];
    const float* ln3g = (const float*)d_in[26]; const float* ln3b = (const float*)d_in[27];

    const float SC = 0.18033688011112042f;     // 0.125 * log2(e)

    char* W = (char*)d_ws;
    #define OFS(mb) ((void*)(W + (size_t)(mb) * 1024 * 1024))
    ushort* x0b    = (ushort*)OFS(0);
    ushort* encb   = (ushort*)OFS(8);
    ushort* WqkvT1 = (ushort*)OFS(16);
    ushort* Wo1T   = (ushort*)OFS(22);
    ushort* Wq2T   = (ushort*)OFS(24);
    ushort* WkvT2  = (ushort*)OFS(26);
    ushort* Wo2T   = (ushort*)OFS(30);
    ushort* Wf1T   = (ushort*)OFS(32);
    ushort* Wf2T   = (ushort*)OFS(36);
    float*  biasQKV1 = (float*)OFS(40);
    float*  biasKV2  = (float*)((char*)OFS(40) + 16384);
    float*  biasQ2   = (float*)((char*)OFS(40) + 32768);
    ushort* QKV1   = (ushort*)OFS(41);   // [3][B][H][S][D]
    ushort* VT1    = (ushort*)OFS(65);
    ushort* att1b  = (ushort*)OFS(73);
    ushort* o1b    = (ushort*)OFS(81);
    float*  out1f  = (float*)OFS(41);
    ushort* out1b  = (ushort*)OFS(57);
    ushort* Q2     = (ushort*)OFS(65);
    ushort* KV2    = (ushort*)OFS(73);   // [2][B][H][S][D]
    ushort* VT2    = (ushort*)OFS(0);
    ushort* att2b  = (ushort*)OFS(8);
    ushort* o2b    = (ushort*)OFS(65);
    float*  out2f  = (float*)OFS(73);
    ushort* out2b  = (ushort*)OFS(0);
    ushort* ff1b   = (ushort*)OFS(41);
    ushort* ff2b   = (ushort*)OFS(57);
    float*  out    = (float*)d_out;
    const size_t MAT = (size_t)B_ * H_ * S_ * D_;   // 4 Mi elements

    dim3 blk(256);

    // ---- prep: casts, weight transposes (Wq scaled by SC), bias packs ----
    cast_k<<<4096, blk, 0, stream>>>(input, x0b);
    cast_k<<<4096, blk, 0, stream>>>(enc, encb);
    wtrans_k<<<dim3(2, 32, 16), blk, 0, stream>>>(Wq1, WqkvT1,               1024, 64, 64 * 1024, SC);
    wtrans_k<<<dim3(2, 32, 16), blk, 0, stream>>>(Wk1, WqkvT1 + 1024 * 1024, 1024, 64, 64 * 1024, 1.f);
    wtrans_k<<<dim3(2, 32, 16), blk, 0, stream>>>(Wv1, WqkvT1 + 2048 * 1024, 1024, 64, 64 * 1024, 1.f);
    wtrans_k<<<dim3(32, 32, 1), blk, 0, stream>>>(Wo1, Wo1T, 1024, 1024, 0, 1.f);
    wtrans_k<<<dim3(2, 32, 16), blk, 0, stream>>>(Wq2, Wq2T, 1024, 64, 64 * 1024, SC);
    wtrans_k<<<dim3(2, 32, 16), blk, 0, stream>>>(Wk2, WkvT2,               1024, 64, 64 * 1024, 1.f);
    wtrans_k<<<dim3(2, 32, 16), blk, 0, stream>>>(Wv2, WkvT2 + 1024 * 1024, 1024, 64, 64 * 1024, 1.f);
    wtrans_k<<<dim3(32, 32, 1), blk, 0, stream>>>(Wo2, Wo2T, 1024, 1024, 0, 1.f);
    wtrans_k<<<dim3(64, 32, 1), blk, 0, stream>>>(Wf1, Wf1T, 1024, 2048, 0, 1.f);
    wtrans_k<<<dim3(32, 64, 1), blk, 0, stream>>>(Wf2, Wf2T, 2048, 1024, 0, 1.f);
    copyf_k<<<4, blk, 0, stream>>>(bq1, biasQKV1,        SC,  1024);
    copyf_k<<<4, blk, 0, stream>>>(bk1, biasQKV1 + 1024, 1.f, 1024);
    copyf_k<<<4, blk, 0, stream>>>(bv1, biasQKV1 + 2048, 1.f, 1024);
    copyf_k<<<4, blk, 0, stream>>>(bk2, biasKV2,         1.f, 1024);
    copyf_k<<<4, blk, 0, stream>>>(bv2, biasKV2 + 1024,  1.f, 1024);
    copyf_k<<<4, blk, 0, stream>>>(bq2, biasQ2,          SC,  1024);

    // ---- masked self-attention ----
    gemm_bf16_k<2, 0><<<dim3(24, 32), blk, 0, stream>>>(x0b, WqkvT1, biasQKV1, QKV1, 3072, 1024);
    vtrans_k<<<dim3(2, 64, 32), blk, 0, stream>>>(QKV1 + 2 * MAT, VT1);
    fattn_k<1><<<dim3(1024), blk, 0, stream>>>(QKV1, QKV1 + MAT, VT1, att1b, S_);
    gemm_bf16_k<1, 0><<<dim3(8, 32), blk, 0, stream>>>(att1b, Wo1T, bo1, o1b, 1024, 1024);
    ln_k<1><<<dim3(R_), blk, 0, stream>>>(o1b, input, ln1g, ln1b, out1f, out1b);

    // ---- cross-attention ----
    gemm_bf16_k<2, 0><<<dim3(8, 32), blk, 0, stream>>>(out1b, Wq2T, biasQ2, Q2, 1024, 1024);
    gemm_bf16_k<2, 0><<<dim3(16, 32), blk, 0, stream>>>(encb, WkvT2, biasKV2, KV2, 2048, 1024);
    vtrans_k<<<dim3(2, 64, 32), blk, 0, stream>>>(KV2 + MAT, VT2);
    fattn_k<0><<<dim3(1024), blk, 0, stream>>>(Q2, KV2, VT2, att2b, S_);
    gemm_bf16_k<1, 0><<<dim3(8, 32), blk, 0, stream>>>(att2b, Wo2T, bo2, o2b, 1024, 1024);
    ln_k<1><<<dim3(R_), blk, 0, stream>>>(o2b, out1f, ln2g, ln2b, out2f, out2b);

    // ---- FFN ----
    gemm_bf16_k<1, 1><<<dim3(16, 32), blk, 0, stream>>>(out2b, Wf1T, bf1, ff1b, 2048, 1024);
    gemm_bf16_k<1, 0><<<dim3(8, 32), blk, 0, stream>>>(ff1b, Wf2T, bf2, ff2b, 1024, 2048);
    ln_k<0><<<dim3(R_), blk, 0, stream>>>(ff2b, out2f, ln3g, ln3b, out, nullptr);
    #undef OFS
}

// Round 8
// 346.986 us; speedup vs baseline: 8.2550x; 1.2048x over previous
//
#include <hip/hip_runtime.h>
#include <math.h>

#define B_ 2
#define S_ 2048
#define M_ 1024
#define H_ 16
#define D_ 64
#define R_ (B_*S_)          // 4096 rows

typedef __attribute__((ext_vector_type(8))) short short8v;   // 8 bf16 = 4 VGPR
typedef __attribute__((ext_vector_type(4))) float float4v;

__device__ __forceinline__ float4 ld4(const float* p) {
    return *(const float4* __restrict__)p;
}

__device__ __forceinline__ ushort f2bf(float f) {            // RNE
    union { float f; unsigned u; } x; x.f = f;
    unsigned u = x.u + 0x7fffu + ((x.u >> 16) & 1u);
    return (ushort)(u >> 16);
}
__device__ __forceinline__ float bf2f(ushort s) {
    union { unsigned u; float f; } x; x.u = ((unsigned)s) << 16; return x.f;
}
__device__ __forceinline__ unsigned cvtpk(float lo, float hi) {
    unsigned r;
    asm("v_cvt_pk_bf16_f32 %0, %1, %2" : "=v"(r) : "v"(lo), "v"(hi));
    return r;
}
#if __has_builtin(__builtin_amdgcn_exp2f)
__device__ __forceinline__ float fexp2(float x) { return __builtin_amdgcn_exp2f(x); }
#else
__device__ __forceinline__ float fexp2(float x) { return exp2f(x); }
#endif
#if __has_builtin(__builtin_amdgcn_rcpf)
__device__ __forceinline__ float frcp(float x) { return __builtin_amdgcn_rcpf(x); }
#else
__device__ __forceinline__ float frcp(float x) { return 1.f / x; }
#endif
__device__ __forceinline__ float4v mfma16(short8v a, short8v b, float4v c) {
    return __builtin_amdgcn_mfma_f32_16x16x32_bf16(a, b, c, 0, 0, 0);
}
__device__ __forceinline__ void glds16(const void* g, void* l) {
    __builtin_amdgcn_global_load_lds(
        (const __attribute__((address_space(1))) void*)g,
        (__attribute__((address_space(3))) void*)l, 16, 0, 0);
}

// ---------------------------------------------------------------------------
// prep kernels (fused)
// ---------------------------------------------------------------------------
// both input casts in one launch: grid 8192, first 4096 blocks -> a, rest -> b
__global__ __launch_bounds__(256) void cast2_k(const float* __restrict__ a,
                                               const float* __restrict__ b,
                                               ushort* __restrict__ oa,
                                               ushort* __restrict__ ob) {
    size_t u = (size_t)blockIdx.x * 256 + threadIdx.x;       // float4 units
    const float* in; ushort* out;
    if (u < (1u << 20)) { in = a; out = oa; }
    else { u -= (1u << 20); in = b; out = ob; }
    float4 v = ld4(in + u * 4);
    ushort4 o = { f2bf(v.x), f2bf(v.y), f2bf(v.z), f2bf(v.w) };
    *(ushort4*)&out[u * 4] = o;
}

// all 6 bias packs in one launch: grid 24 (4 blocks per 1024-elem segment)
__global__ __launch_bounds__(256) void biasp_k(
    const float* __restrict__ q1, const float* __restrict__ k1,
    const float* __restrict__ v1, const float* __restrict__ k2,
    const float* __restrict__ v2, const float* __restrict__ q2,
    float* __restrict__ dst, float SCv) {
    const int seg = blockIdx.x >> 2;
    const int li = (blockIdx.x & 3) * 256 + threadIdx.x;
    const float* s; int off; float sc;
    switch (seg) {
        case 0: s = q1; off = 0;    sc = SCv; break;
        case 1: s = k1; off = 1024; sc = 1.f; break;
        case 2: s = v1; off = 2048; sc = 1.f; break;
        case 3: s = k2; off = 4096; sc = 1.f; break;
        case 4: s = v2; off = 5120; sc = 1.f; break;
        default: s = q2; off = 8192; sc = SCv; break;
    }
    dst[off + li] = s[li] * sc;
}

// all six head-stacked weights ([16][1024][64] -> [h][64][1024]) in one launch
// z = blockIdx.z: src = z>>4 in {Wq1,Wk1,Wv1,Wq2,Wk2,Wv2}, head = z&15
__global__ __launch_bounds__(256) void wtransH_k(
    const float* __restrict__ s0, const float* __restrict__ s1,
    const float* __restrict__ s2, const float* __restrict__ s3,
    const float* __restrict__ s4, const float* __restrict__ s5,
    ushort* __restrict__ oQKV1, ushort* __restrict__ oQ2,
    ushort* __restrict__ oKV2, float SCv) {
    __shared__ float t[32][33];
    const int z = blockIdx.z, s6 = z >> 4, h = z & 15;
    const float* srcs[6] = { s0, s1, s2, s3, s4, s5 };
    const float* ib = srcs[s6] + (size_t)h * 1024 * 64;
    ushort* ob;
    if (s6 < 3)       ob = oQKV1 + (size_t)s6 * (1024 * 1024) + (size_t)h * (64 * 1024);
    else if (s6 == 3) ob = oQ2 + (size_t)h * (64 * 1024);
    else              ob = oKV2 + (size_t)(s6 - 4) * (1024 * 1024) + (size_t)h * (64 * 1024);
    const float scale = (s6 == 0 || s6 == 3) ? SCv : 1.f;
    const int k0 = blockIdx.y * 32, n0 = blockIdx.x * 32;
    const int tx = threadIdx.x & 31, ty = threadIdx.x >> 5;
    #pragma unroll
    for (int i = 0; i < 4; ++i)
        t[ty + i * 8][tx] = ib[(size_t)(k0 + ty + i * 8) * 64 + n0 + tx];
    __syncthreads();
    #pragma unroll
    for (int i = 0; i < 4; ++i)
        ob[(size_t)(n0 + ty + i * 8) * 1024 + k0 + tx] = f2bf(t[tx][ty + i * 8] * scale);
}

// generic fp32 [K][N] -> bf16 [N][K] (used for Wo1/Wo2 pair, Wf1, Wf2)
__global__ __launch_bounds__(256) void wtrans_k(const float* __restrict__ inA,
                                                const float* __restrict__ inB,
                                                ushort* __restrict__ outA,
                                                ushort* __restrict__ outB,
                                                int K, int N) {
    __shared__ float t[32][33];
    const float* ib = blockIdx.z ? inB : inA;
    ushort* ob = blockIdx.z ? outB : outA;
    const int k0 = blockIdx.y * 32, n0 = blockIdx.x * 32;
    const int tx = threadIdx.x & 31, ty = threadIdx.x >> 5;
    #pragma unroll
    for (int i = 0; i < 4; ++i)
        t[ty + i * 8][tx] = ib[(size_t)(k0 + ty + i * 8) * N + n0 + tx];
    __syncthreads();
    #pragma unroll
    for (int i = 0; i < 4; ++i)
        ob[(size_t)(n0 + ty + i * 8) * K + k0 + tx] = f2bf(t[tx][ty + i * 8]);
}

// ---------------------------------------------------------------------------
// bf16 MFMA GEMM, TMxTN tile, BK=32, 256 thr (4 waves 2x2), m97 structure.
// A: bf16 [4096][K] row-major. Bt: bf16 [N][K] (k-contiguous). bias fp32 [N].
// OUTMODE: 0 = fp32 row-major, 1 = bf16 row-major,
//          2 = bf16 [mat][B][H][S][D]; matrix matV goes to Cvt as [BH][64][S]
// ---------------------------------------------------------------------------
template<int TM, int TN, int OUTMODE, int ACT>
__global__ __launch_bounds__(256) void gemm_bf16_k(
    const ushort* __restrict__ A, const ushort* __restrict__ Bt,
    const float* __restrict__ bias, void* __restrict__ C,
    ushort* __restrict__ Cvt, int matV, int N, int K)
{
    constexpr int NI = TM / 32;
    constexpr int NJ = TN / 32;
    __shared__ __align__(16) ushort At[TM * 32];
    __shared__ __align__(16) ushort Bts[TN * 32];
    const int tid = threadIdx.x, lane = tid & 63, w = tid >> 6;
    const int wm = w >> 1, wn = w & 1;
    const int q = lane & 15, g = lane >> 4;
    const int m0 = blockIdx.y * TM, n0 = blockIdx.x * TN;

    float4v acc[NI][NJ];
    #pragma unroll
    for (int i = 0; i < NI; ++i)
        #pragma unroll
        for (int j = 0; j < NJ; ++j) acc[i][j] = (float4v){0.f, 0.f, 0.f, 0.f};

    for (int k0 = 0; k0 < K; k0 += 32) {
        #pragma unroll
        for (int t = 0; t < TM / 64; ++t) {
            const int cb = (w * (TM / 64) + t) * 64;
            const int c = cb + lane;
            glds16(&A[(size_t)(m0 + (c >> 2)) * K + k0 + (c & 3) * 8], &At[cb * 8]);
        }
        #pragma unroll
        for (int t = 0; t < TN / 64; ++t) {
            const int cb = (w * (TN / 64) + t) * 64;
            const int c = cb + lane;
            glds16(&Bt[(size_t)(n0 + (c >> 2)) * K + k0 + (c & 3) * 8], &Bts[cb * 8]);
        }
        __syncthreads();
        short8v af[NI], bf[NJ];
        #pragma unroll
        for (int i = 0; i < NI; ++i)
            af[i] = *(const short8v*)&At[(wm * (TM / 2) + i * 16 + q) * 32 + g * 8];
        #pragma unroll
        for (int j = 0; j < NJ; ++j)
            bf[j] = *(const short8v*)&Bts[(wn * (TN / 2) + j * 16 + q) * 32 + g * 8];
        #pragma unroll
        for (int i = 0; i < NI; ++i)
            #pragma unroll
            for (int j = 0; j < NJ; ++j)
                acc[i][j] = mfma16(af[i], bf[j], acc[i][j]);
        __syncthreads();
    }

    float bcol[NJ];
    #pragma unroll
    for (int j = 0; j < NJ; ++j) bcol[j] = bias[n0 + wn * (TN / 2) + j * 16 + q];

    #pragma unroll
    for (int i = 0; i < NI; ++i) {
        const int rowg0 = m0 + wm * (TM / 2) + i * 16 + g * 4;
        #pragma unroll
        for (int j = 0; j < NJ; ++j) {
            const int colg = n0 + wn * (TN / 2) + j * 16 + q;
            float v[4];
            #pragma unroll
            for (int r = 0; r < 4; ++r) {
                v[r] = acc[i][j][r] + bcol[j];
                if (ACT) v[r] = fmaxf(v[r], 0.f);
            }
            if (OUTMODE == 0) {
                #pragma unroll
                for (int r = 0; r < 4; ++r)
                    ((float*)C)[(size_t)(rowg0 + r) * N + colg] = v[r];
            } else if (OUTMODE == 1) {
                #pragma unroll
                for (int r = 0; r < 4; ++r)
                    ((ushort*)C)[(size_t)(rowg0 + r) * N + colg] = f2bf(v[r]);
            } else {
                const int mat = colg >> 10, h = (colg >> 6) & 15, d = colg & 63;
                const int bb = rowg0 >> 11, s0 = rowg0 & 2047;
                if (mat == matV) {   // V -> transposed layout [bh][d][s], 4 s contiguous
                    uint2 pv;
                    pv.x = cvtpk(v[0], v[1]);
                    pv.y = cvtpk(v[2], v[3]);
                    *(uint2*)&Cvt[((size_t)(bb * H_ + h) * D_ + d) * S_ + s0] = pv;
                } else {
                    #pragma unroll
                    for (int r = 0; r < 4; ++r)
                        ((ushort*)C)[((((size_t)(mat * B_ + bb) * H_ + h) * S_) + s0 + r) * D_ + d] = f2bf(v[r]);
                }
            }
        }
    }
}

// ---------------------------------------------------------------------------
// Flash attention, bf16 MFMA, swapped formulation.
// 256 thr = 4 waves x 16 q-rows (q-tile 64). KV tile 64, double-buffered.
// Raw v_exp_f32 (domain x<=0 -> exact); T13 defer-rescale; T5 setprio.
// ---------------------------------------------------------------------------
template<int CAUSAL>
__global__ __launch_bounds__(256, 4) void fattn_k(
    const ushort* __restrict__ Qg, const ushort* __restrict__ Kg,
    const ushort* __restrict__ VTg, ushort* __restrict__ Og, int Skv)
{
    __shared__ __align__(16) ushort Kt[2][64 * 64];   // [kv][d] swizzled, 8 KB x2
    __shared__ __align__(16) ushort Vt[2][64 * 64];   // [d][kv] swizzled, 8 KB x2
    __shared__ __align__(16) ushort Pt[64 * 64];      // P^T in-loop; O at end. 8 KB
    const int tid = threadIdx.x, lane = tid & 63, w = tid >> 6;   // w 0..3
    const int g = lane >> 4, q = lane & 15;
    const int id = blockIdx.x;
    const int bh = id & 31;
    const int qb = CAUSAL ? (31 - (id >> 5)) : (id >> 5);
    const int q0b = qb * 64;
    const int q0w = q0b + w * 16;
    const int qr = w * 16 + q;

    // staging sources (2 chunks per thread per matrix), pre-swizzled
    const int c0 = tid, c1 = tid + 256;
    const ushort* kS0 = Kg + ((size_t)bh * Skv + (c0 >> 3)) * 64 + (((c0 & 7) ^ ((c0 >> 3) & 7)) * 8);
    const ushort* kS1 = Kg + ((size_t)bh * Skv + (c1 >> 3)) * 64 + (((c1 & 7) ^ ((c1 >> 3) & 7)) * 8);
    const ushort* vS0 = VTg + ((size_t)bh * 64 + (c0 >> 3)) * (size_t)Skv + (((c0 & 7) ^ ((c0 >> 3) & 7)) * 8);
    const ushort* vS1 = VTg + ((size_t)bh * 64 + (c1 >> 3)) * (size_t)Skv + (((c1 & 7) ^ ((c1 >> 3) & 7)) * 8);

#define STAGE(nb) do { \
        glds16(kS0, &Kt[nb][(w * 64) * 8]); \
        glds16(kS1, &Kt[nb][(256 + w * 64) * 8]); \
        glds16(vS0, &Vt[nb][(w * 64) * 8]); \
        glds16(vS1, &Vt[nb][(256 + w * 64) * 8]); \
        kS0 += 64 * 64; kS1 += 64 * 64; vS0 += 64; vS1 += 64; } while (0)

    // Q fragments (Q pre-scaled in projection)
    short8v qf[2];
    #pragma unroll
    for (int kf = 0; kf < 2; ++kf)
        qf[kf] = *(const short8v*)&Qg[((size_t)bh * S_ + q0w + q) * 64 + kf * 32 + g * 8];

    // loop-invariant LDS byte bases
    const int swz = (g ^ (q & 7)) << 4;
    const int ktB = q * 128 + swz;                    // + kvf*2048 ; ^ (kf<<6)
    const int vtB = q * 128 + swz;                    // + df*2048  ; ^ (kf<<6)
    const int pfB = qr * 128 + swz;                   // ^ (kf<<6)
    const int poB = qr * 128 + ((((g >> 1) ^ (q & 7)) << 4) | ((g & 1) << 3)); // ^ (kvf<<5)

    float4v oacc[4];
    #pragma unroll
    for (int d2 = 0; d2 < 4; ++d2) oacc[d2] = (float4v){0.f, 0.f, 0.f, 0.f};
    float m_ = -1e30f, l_ = 0.f;

    const int ktiles = CAUSAL ? (qb + 1) : (Skv >> 6);
    int cur = 0;

    STAGE(0);
    __syncthreads();

    for (int kt = 0; kt < ktiles; ++kt) {
        if (kt + 1 < ktiles) STAGE(cur ^ 1);          // issue-early: flies under compute
        const char* ktp = (const char*)Kt + cur * 8192;
        const char* vtp = (const char*)Vt + cur * 8192;

        // S^T = K . Q^T  (rows kv, cols q); st[kvf][r] = S^T[kvf*16+g*4+r][q]
        float4v st[4];
        __builtin_amdgcn_s_setprio(1);
        #pragma unroll
        for (int kvf = 0; kvf < 4; ++kvf) {
            short8v k0 = *(const short8v*)(ktp + (ktB + kvf * 2048));
            short8v k1 = *(const short8v*)(ktp + ((ktB + kvf * 2048) ^ 64));
            st[kvf] = mfma16(k0, qf[0], (float4v){0.f, 0.f, 0.f, 0.f});
            st[kvf] = mfma16(k1, qf[1], st[kvf]);
        }
        __builtin_amdgcn_s_setprio(0);

        if (CAUSAL && kt == ktiles - 1) {             // diagonal tile (kv0 == q0b)
            const int qg_ = q0w + q;
            #pragma unroll
            for (int kvf = 0; kvf < 4; ++kvf)
                #pragma unroll
                for (int r = 0; r < 4; ++r)
                    if (q0b + kvf * 16 + g * 4 + r > qg_) st[kvf][r] = -1e9f;
        }

        // row max (tree + 2 shuffles)
        float mA[4];
        #pragma unroll
        for (int kvf = 0; kvf < 4; ++kvf)
            mA[kvf] = fmaxf(fmaxf(st[kvf][0], st[kvf][1]), fmaxf(st[kvf][2], st[kvf][3]));
        float mx = fmaxf(fmaxf(mA[0], mA[1]), fmaxf(mA[2], mA[3]));
        mx = fmaxf(mx, __shfl_xor(mx, 16));
        mx = fmaxf(mx, __shfl_xor(mx, 32));

        if (!__all(mx <= m_)) {                       // T13: skip is exact (f == 1)
            const float nm = fmaxf(m_, mx);
            const float f = fexp2(m_ - nm);
            l_ *= f;
            #pragma unroll
            for (int d2 = 0; d2 < 4; ++d2) oacc[d2] = oacc[d2] * f;
            m_ = nm;
        }

        // exp + per-lane partial sum (row-reduce deferred to epilogue)
        float sA[4];
        #pragma unroll
        for (int kvf = 0; kvf < 4; ++kvf) {
            #pragma unroll
            for (int r = 0; r < 4; ++r) st[kvf][r] = fexp2(st[kvf][r] - m_);
            sA[kvf] = (st[kvf][0] + st[kvf][1]) + (st[kvf][2] + st[kvf][3]);
        }
        l_ += (sA[0] + sA[1]) + (sA[2] + sA[3]);

        // pack P^T rows into Pt (own wave's rows only; same-wave write->read)
        #pragma unroll
        for (int kvf = 0; kvf < 4; ++kvf) {
            uint2 pv;
            pv.x = cvtpk(st[kvf][0], st[kvf][1]);
            pv.y = cvtpk(st[kvf][2], st[kvf][3]);
            *(uint2*)((char*)Pt + (poB ^ (kvf << 5))) = pv;
        }

        // O^T += V^T . P^T
        short8v pf[2];
        #pragma unroll
        for (int kf = 0; kf < 2; ++kf)
            pf[kf] = *(const short8v*)((const char*)Pt + (pfB ^ (kf << 6)));
        __builtin_amdgcn_s_setprio(1);
        #pragma unroll
        for (int df = 0; df < 4; ++df) {
            #pragma unroll
            for (int kf = 0; kf < 2; ++kf) {
                short8v vfr = *(const short8v*)(vtp + ((vtB + df * 2048) ^ (kf << 6)));
                oacc[df] = mfma16(vfr, pf[kf], oacc[df]);
            }
        }
        __builtin_amdgcn_s_setprio(0);

        __syncthreads();       // drains stage(t+1) vmcnt + protects Kt/Vt[cur]
        cur ^= 1;
    }
#undef STAGE

    // row sum across the 4 g-lanes, then normalize
    float lr = l_;
    lr += __shfl_xor(lr, 16);
    lr += __shfl_xor(lr, 32);
    const float inv = frcp(lr);

    // stage O into Pt (own wave's rows -- no barrier needed before writes)
    #pragma unroll
    for (int df = 0; df < 4; ++df) {
        uint2 ov;
        ov.x = cvtpk(oacc[df][0] * inv, oacc[df][1] * inv);
        ov.y = cvtpk(oacc[df][2] * inv, oacc[df][3] * inv);
        *(uint2*)((char*)Pt + qr * 128 +
                  ((((2 * df + (g >> 1)) ^ (q & 7)) << 4) | ((g & 1) << 3))) = ov;
    }
    __syncthreads();
    const int b = bh >> 4, h = bh & 15;
    #pragma unroll
    for (int t = 0; t < 2; ++t) {
        const int c = t * 256 + tid;
        const int qrow = c >> 3, ch = c & 7;
        short8v v = *(const short8v*)((char*)Pt + qrow * 128 + ((ch ^ (qrow & 7)) << 4));
        *(short8v*)&Og[((size_t)(b * S_ + q0b + qrow)) * M_ + h * 64 + ch * 8] = v;
    }
}

// ---------------------------------------------------------------------------
// Fused residual-add + LayerNorm. X bf16, residual fp32; emits fp32 (+bf16).
// ---------------------------------------------------------------------------
template<int EMITB>
__global__ __launch_bounds__(256) void ln_k(
    const ushort* __restrict__ X, const float* __restrict__ Rz,
    const float* __restrict__ g, const float* __restrict__ be,
    float* __restrict__ outf, ushort* __restrict__ outb)
{
    __shared__ float red[8];
    const int row = blockIdx.x, tid = threadIdx.x;
    const int lane = tid & 63, w = tid >> 6;

    ushort4 xu = *(const ushort4*)&X[(size_t)row * M_ + tid * 4];
    float4 rr = ld4(Rz + (size_t)row * M_ + tid * 4);
    float4 x = make_float4(bf2f(xu.x) + rr.x, bf2f(xu.y) + rr.y,
                           bf2f(xu.z) + rr.z, bf2f(xu.w) + rr.w);

    float sm = x.x + x.y + x.z + x.w;
    #pragma unroll
    for (int off = 1; off < 64; off <<= 1) sm += __shfl_xor(sm, off);
    if (lane == 0) red[w] = sm;
    __syncthreads();
    const float mean = (red[0] + red[1] + red[2] + red[3]) * (1.f / M_);

    x.x -= mean; x.y -= mean; x.z -= mean; x.w -= mean;
    float vs = x.x * x.x + x.y * x.y + x.z * x.z + x.w * x.w;
    #pragma unroll
    for (int off = 1; off < 64; off <<= 1) vs += __shfl_xor(vs, off);
    if (lane == 0) red[4 + w] = vs;
    __syncthreads();
    const float var = (red[4] + red[5] + red[6] + red[7]) * (1.f / M_);
    const float rs = rsqrtf(var + 1e-5f);

    float4 gg = ld4(g + tid * 4), bb = ld4(be + tid * 4);
    float4 y = make_float4(x.x * rs * gg.x + bb.x, x.y * rs * gg.y + bb.y,
                           x.z * rs * gg.z + bb.z, x.w * rs * gg.w + bb.w);
    *(float4*)(outf + (size_t)row * M_ + tid * 4) = y;
    if (EMITB) {
        ushort4 ob = { f2bf(y.x), f2bf(y.y), f2bf(y.z), f2bf(y.w) };
        *(ushort4*)&outb[(size_t)row * M_ + tid * 4] = ob;
    }
}

// ---------------------------------------------------------------------------
extern "C" void kernel_launch(void* const* d_in, const int* in_sizes, int n_in,
                              void* d_out, int out_size, void* d_ws, size_t ws_size,
                              hipStream_t stream)
{
    const float* input = (const float*)d_in[0];
    const float* enc   = (const float*)d_in[1];
    const float* Wq1 = (const float*)d_in[2];  const float* bq1 = (const float*)d_in[3];
    const float* Wk1 = (const float*)d_in[4];  const float* bk1 = (const float*)d_in[5];
    const float* Wv1 = (const float*)d_in[6];  const float* bv1 = (const float*)d_in[7];
    const float* Wo1 = (const float*)d_in[8];  const float* bo1 = (const float*)d_in[9];
    const float* ln1g = (const float*)d_in[10]; const float* ln1b = (const float*)d_in[11];
    const float* Wq2 = (const float*)d_in[12]; const float* bq2 = (const float*)d_in[13];
    const float* Wk2 = (const float*)d_in[14]; const float* bk2 = (const float*)d_in[15];
    const float* Wv2 = (const float*)d_in[16]; const float* bv2 = (const float*)d_in[17];
    const float* Wo2 = (const float*)d_in[18]; const float* bo2 = (const float*)d_in[19];
    const float* ln2g = (const float*)d_in[20]; const float* ln2b = (const float*)d_in[21];
    const float* Wf1 = (const float*)d_in[22]; const float* bf1 = (const float*)d_in[23];
    const float* Wf2 = (const float*)d_in[24]; const float* bf2 = (const float*)d_in[25];
    const float* ln3g = (const float*)d_in[26]; const float* ln3b = (const float*)d_in[27];

    const float SC = 0.18033688011112042f;     // 0.125 * log2(e)

    char* W = (char*)d_ws;
    #define OFS(mb) ((void*)(W + (size_t)(mb) * 1024 * 1024))
    ushort* x0b    = (ushort*)OFS(0);
    ushort* encb   = (ushort*)OFS(8);
    ushort* WqkvT1 = (ushort*)OFS(16);
    ushort* Wo1T   = (ushort*)OFS(22);
    ushort* Wq2T   = (ushort*)OFS(24);
    ushort* WkvT2  = (ushort*)OFS(26);
    ushort* Wo2T   = (ushort*)OFS(30);
    ushort* Wf1T   = (ushort*)OFS(32);
    ushort* Wf2T   = (ushort*)OFS(36);
    float*  biasQKV1 = (float*)OFS(40);
    float*  biasKV2  = (float*)((char*)OFS(40) + 16384);
    float*  biasQ2   = (float*)((char*)OFS(40) + 32768);
    ushort* QKV1   = (ushort*)OFS(41);   // [3][B][H][S][D] (V region unused)
    ushort* VT1    = (ushort*)OFS(65);
    ushort* att1b  = (ushort*)OFS(73);
    ushort* o1b    = (ushort*)OFS(81);
    float*  out1f  = (float*)OFS(41);
    ushort* out1b  = (ushort*)OFS(57);
    ushort* Q2     = (ushort*)OFS(65);
    ushort* KV2    = (ushort*)OFS(73);   // [2][B][H][S][D] (V region unused)
    ushort* VT2    = (ushort*)OFS(0);
    ushort* att2b  = (ushort*)OFS(8);
    ushort* o2b    = (ushort*)OFS(65);
    float*  out2f  = (float*)OFS(73);
    ushort* out2b  = (ushort*)OFS(0);
    ushort* ff1b   = (ushort*)OFS(41);
    ushort* ff2b   = (ushort*)OFS(57);
    float*  out    = (float*)d_out;
    const size_t MAT = (size_t)B_ * H_ * S_ * D_;   // 4 Mi elements

    dim3 blk(256);

    // ---- prep (6 launches) ----
    cast2_k<<<8192, blk, 0, stream>>>(input, enc, x0b, encb);
    biasp_k<<<24, blk, 0, stream>>>(bq1, bk1, bv1, bk2, bv2, bq2, biasQKV1, SC);
    wtransH_k<<<dim3(2, 32, 96), blk, 0, stream>>>(Wq1, Wk1, Wv1, Wq2, Wk2, Wv2,
                                                   WqkvT1, Wq2T, WkvT2, SC);
    wtrans_k<<<dim3(32, 32, 2), blk, 0, stream>>>(Wo1, Wo2, Wo1T, Wo2T, 1024, 1024);
    wtrans_k<<<dim3(64, 32, 1), blk, 0, stream>>>(Wf1, Wf1, Wf1T, Wf1T, 1024, 2048);
    wtrans_k<<<dim3(32, 64, 1), blk, 0, stream>>>(Wf2, Wf2, Wf2T, Wf2T, 2048, 1024);

    // ---- masked self-attention ----
    gemm_bf16_k<128, 128, 2, 0><<<dim3(24, 32), blk, 0, stream>>>(
        x0b, WqkvT1, biasQKV1, QKV1, VT1, 2, 3072, 1024);
    fattn_k<1><<<dim3(1024), blk, 0, stream>>>(QKV1, QKV1 + MAT, VT1, att1b, S_);
    gemm_bf16_k<64, 64, 1, 0><<<dim3(16, 64), blk, 0, stream>>>(
        att1b, Wo1T, bo1, o1b, nullptr, 9, 1024, 1024);
    ln_k<1><<<dim3(R_), blk, 0, stream>>>(o1b, input, ln1g, ln1b, out1f, out1b);

    // ---- cross-attention ----
    gemm_bf16_k<64, 64, 2, 0><<<dim3(16, 64), blk, 0, stream>>>(
        out1b, Wq2T, biasQ2, Q2, nullptr, 9, 1024, 1024);
    gemm_bf16_k<128, 128, 2, 0><<<dim3(16, 32), blk, 0, stream>>>(
        encb, WkvT2, biasKV2, KV2, VT2, 1, 2048, 1024);
    fattn_k<0><<<dim3(1024), blk, 0, stream>>>(Q2, KV2, VT2, att2b, S_);
    gemm_bf16_k<64, 64, 1, 0><<<dim3(16, 64), blk, 0, stream>>>(
        att2b, Wo2T, bo2, o2b, nullptr, 9, 1024, 1024);
    ln_k<1><<<dim3(R_), blk, 0, stream>>>(o2b, out1f, ln2g, ln2b, out2f, out2b);

    // ---- FFN ----
    gemm_bf16_k<128, 64, 1, 1><<<dim3(32, 32), blk, 0, stream>>>(
        out2b, Wf1T, bf1, ff1b, nullptr, 9, 2048, 1024);
    gemm_bf16_k<64, 64, 1, 0><<<dim3(16, 64), blk, 0, stream>>>(
        ff1b, Wf2T, bf2, ff2b, nullptr, 9, 1024, 2048);
    ln_k<0><<<dim3(R_), blk, 0, stream>>>(ff2b, out2f, ln3g, ln3b, out, nullptr);
    #undef OFS
}